// Round 12
// baseline (221.832 us; speedup 1.0000x reference)
//
#include <hip/hip_runtime.h>
#include <hip/hip_bf16.h>
#include <math.h>

#define B_    2
#define L_    2048
#define E_    1024
#define H_    16
#define DH_   64
#define HID_  4096
#define NROW_ (B_*L_)   // 4096
#define BH_   (B_*H_)   // 32

// 0.125 (1/sqrt(DH)) * log2(e): Q pre-scale so P = exp2(S')
#define QSCL  0.18033688011112042f

typedef __attribute__((ext_vector_type(8)))  short    short8v;
typedef _Float16 half8v __attribute__((ext_vector_type(8)));
typedef __attribute__((ext_vector_type(16))) float    f32x16;

#define MFMA32(A, Bv, C) __builtin_amdgcn_mfma_f32_32x32x16_bf16((A), (Bv), (C), 0, 0, 0)
#define MFMAH(A, Bv, C)  __builtin_amdgcn_mfma_f32_32x32x16_f16((A), (Bv), (C), 0, 0, 0)

#define WAITV(N) asm volatile("s_waitcnt vmcnt(" #N ")" ::: "memory")
#define SBAR()   __builtin_amdgcn_s_barrier()

// float->bf16 round-half-up (2 ops).
__device__ __forceinline__ unsigned short f2bf(float f) {
    union { float f; unsigned u; } v; v.f = f;
    return (unsigned short)((v.u + 0x8000u) >> 16);
}
// pack two floats -> {bf16(hi), bf16(lo)} in 3 VALU ops via v_perm_b32
__device__ __forceinline__ unsigned pack2_bf16(float lo, float hi) {
    union { float f; unsigned u; } a, b; a.f = lo; b.f = hi;
    return __builtin_amdgcn_perm(b.u + 0x8000u, a.u + 0x8000u, 0x07060302u);
}
__device__ __forceinline__ float bf2f(unsigned short u) {
    union { unsigned u; float f; } v; v.u = ((unsigned)u) << 16;
    return v.f;
}

// async global->LDS, 16B per lane. Dest is wave-uniform base + lane*16.
__device__ __forceinline__ void gl_lds16(const void* g, void* l) {
    __builtin_amdgcn_global_load_lds(
        (const __attribute__((address_space(1))) unsigned int*)g,
        (__attribute__((address_space(3))) unsigned int*)l, 16, 0, 0);
}

// Abramowitz-Stegun 7.1.26, |abs err| < 1.5e-7
__device__ __forceinline__ float erf_fast(float v) {
    float a = fabsf(v);
    float t = __builtin_amdgcn_rcpf(1.0f + 0.3275911f * a);
    float p = t * (0.254829592f + t * (-0.284496736f + t * (1.421413741f +
              t * (-1.453152027f + t * 1.061405429f))));
    float r = 1.0f - p * __expf(-a * a);
    return copysignf(r, v);
}

// ---------------------------------------------------------------------------
// Prep A: cast z (fp32) -> zh (fp16), same layout.
// ---------------------------------------------------------------------------
__global__ __launch_bounds__(256) void zh_prep(
    const float* __restrict__ z, _Float16* __restrict__ zh)
{
    const size_t i = ((size_t)blockIdx.x * 256 + threadIdx.x) * 8;
    float4 a = *(const float4*)&z[i];
    float4 b = *(const float4*)&z[i + 4];
    union { _Float16 h[8]; half8v v; } o;
    o.h[0] = (_Float16)a.x; o.h[1] = (_Float16)a.y;
    o.h[2] = (_Float16)a.z; o.h[3] = (_Float16)a.w;
    o.h[4] = (_Float16)b.x; o.h[5] = (_Float16)b.y;
    o.h[6] = (_Float16)b.z; o.h[7] = (_Float16)b.w;
    *(half8v*)&zh[i] = o.v;
}

// ---------------------------------------------------------------------------
// Prep B: transpose+cast Wq/Wk/Wv (ExE fp32) -> T* (n-major fp16, contiguous
// so Tq base acts as a fused [3072][1024] weight).
// ---------------------------------------------------------------------------
__global__ __launch_bounds__(256) void wprep3(
    const float* __restrict__ Wq, const float* __restrict__ Wk,
    const float* __restrict__ Wv,
    _Float16* __restrict__ Tq, _Float16* __restrict__ Tk,
    _Float16* __restrict__ Tv)
{
    const float* src = (blockIdx.z == 0) ? Wq : (blockIdx.z == 1) ? Wk : Wv;
    _Float16*    dst = (blockIdx.z == 0) ? Tq : (blockIdx.z == 1) ? Tk : Tv;
    __shared__ float tile[64][65];
    const int t  = threadIdx.x;
    const int r0 = blockIdx.y * 64, c0 = blockIdx.x * 64;
    #pragma unroll
    for (int u = 0; u < 4; ++u) {
        int f = t + 256 * u, row = f >> 4, c4 = (f & 15) << 2;
        *(float4*)&tile[row][c4] = *(const float4*)&src[(size_t)(r0 + row) * E_ + c0 + c4];
    }
    __syncthreads();
    #pragma unroll
    for (int u = 0; u < 4; ++u) {
        int f = t + 256 * u, c = f >> 4, r4 = (f & 15) << 2;
        union { _Float16 h[4]; uint2 u2; } pk;
        pk.h[0] = (_Float16)tile[r4 + 0][c];
        pk.h[1] = (_Float16)tile[r4 + 1][c];
        pk.h[2] = (_Float16)tile[r4 + 2][c];
        pk.h[3] = (_Float16)tile[r4 + 3][c];
        *(uint2*)&dst[(size_t)(c0 + c) * E_ + r0 + r4] = pk.u2;
    }
}

// ---------------------------------------------------------------------------
// Prep C: transpose+cast W1 (E x HID fp32) -> W1t (HID x E fp16).
// ---------------------------------------------------------------------------
__global__ __launch_bounds__(256) void w1prep(
    const float* __restrict__ W1, _Float16* __restrict__ W1t)
{
    __shared__ float tile[64][65];
    const int t  = threadIdx.x;
    const int r0 = blockIdx.y * 64, c0 = blockIdx.x * 64;
    #pragma unroll
    for (int u = 0; u < 4; ++u) {
        int f = t + 256 * u, row = f >> 4, c4 = (f & 15) << 2;
        *(float4*)&tile[row][c4] = *(const float4*)&W1[(size_t)(r0 + row) * HID_ + c0 + c4];
    }
    __syncthreads();
    #pragma unroll
    for (int u = 0; u < 4; ++u) {
        int f = t + 256 * u, c = f >> 4, r4 = (f & 15) << 2;
        union { _Float16 h[4]; uint2 u2; } pk;
        pk.h[0] = (_Float16)tile[r4 + 0][c];
        pk.h[1] = (_Float16)tile[r4 + 1][c];
        pk.h[2] = (_Float16)tile[r4 + 2][c];
        pk.h[3] = (_Float16)tile[r4 + 3][c];
        *(uint2*)&W1t[(size_t)(c0 + c) * E_ + r0 + r4] = pk.u2;
    }
}

// ---------------------------------------------------------------------------
// Kernel 1: fused QKV projection (single dispatch over n=3072), fp16 MFMA,
// 128x128 tile, BK=64, 4 waves, counted-vmcnt 2-deep pipeline.
// blockIdx.y>>3 selects {Q,K,V}; Tq/Qb bases are contiguous 3x buffers.
// ---------------------------------------------------------------------------
__global__ __launch_bounds__(256) void qkv_mfma(
    const _Float16* __restrict__ zh,
    const _Float16* __restrict__ Tall,      // fused [3072][1024]
    const float* __restrict__ bq, const float* __restrict__ bk,
    const float* __restrict__ bv,
    unsigned short* __restrict__ outQKV)    // Qb | Kb | Vb contiguous
{
    const int which = blockIdx.y >> 3;      // 1024/128 = 8 tiles per weight
    const float* bias = (which == 0) ? bq : (which == 1) ? bk : bv;
    const float  osc  = (which == 0) ? QSCL : 1.0f;
    unsigned short* out = outQKV + (size_t)which * ((size_t)BH_ * L_ * DH_);

    __shared__ _Float16 Ah[2][128 * 64];
    __shared__ _Float16 Bs[2][128 * 64];

    const int t    = threadIdx.x;
    const int lane = t & 63;
    const int w    = t >> 6;
    const int l31  = lane & 31;
    const int hq   = lane >> 5;
    const int wm   = w >> 1, wn = w & 1;
    const int m0   = blockIdx.x * 128;
    const int n0   = blockIdx.y * 128;      // global fused n

    const int srow0 = (lane >> 3);
    const int ssl   = lane & 7;

    f32x16 acc[2][2] = {};

#define QKV_STAGE(bb, kc)                                                          \
    {                                                                              \
        _Pragma("unroll")                                                          \
        for (int u = 0; u < 4; ++u) {                                              \
            int ch  = w * 4 + u;                                                   \
            int row = ch * 8 + srow0;                                              \
            gl_lds16(&zh[(size_t)(m0 + row) * E_ + (kc) * 64 + ((ssl ^ (row & 7)) << 3)], \
                     &Ah[bb][ch * 512]);                                           \
            gl_lds16(&Tall[(size_t)(n0 + row) * E_ + (kc) * 64 + ((ssl ^ (row & 7)) << 3)], \
                     &Bs[bb][ch * 512]);                                           \
        }                                                                          \
    }

    QKV_STAGE(0, 0);
    QKV_STAGE(1, 1);
    __syncthreads();
    int cur = 0;

    for (int kc = 0; kc < 16; ++kc) {
        if (kc < 15) WAITV(8); else WAITV(0);
        SBAR();
        __builtin_amdgcn_s_setprio(1);
        #pragma unroll
        for (int ks = 0; ks < 4; ++ks) {
            half8v fb[2];
            #pragma unroll
            for (int nb = 0; nb < 2; ++nb) {
                int br = wn * 64 + nb * 32 + l31;
                fb[nb] = *(const half8v*)&Bs[cur][br * 64 + (((ks * 2 + hq) ^ (br & 7)) << 3)];
            }
            #pragma unroll
            for (int mb = 0; mb < 2; ++mb) {
                int ar = wm * 64 + mb * 32 + l31;
                half8v fa = *(const half8v*)&Ah[cur][ar * 64 + (((ks * 2 + hq) ^ (ar & 7)) << 3)];
                acc[mb][0] = MFMAH(fa, fb[0], acc[mb][0]);
                acc[mb][1] = MFMAH(fa, fb[1], acc[mb][1]);
            }
        }
        __builtin_amdgcn_s_setprio(0);
        SBAR();
        if (kc + 2 < 16) QKV_STAGE(cur, kc + 2);
        cur ^= 1;
    }

    // epilogue: bias (+ Q scale) + bf16 scatter to (BH,L,DH)
    #pragma unroll
    for (int nb = 0; nb < 2; ++nb) {
        int n  = n0 + wn * 64 + nb * 32 + l31;   // fused n
        int nn = n & 1023;
        int h  = nn >> 6, dh = nn & 63;
        float bb = bias[nn];
        #pragma unroll
        for (int mb = 0; mb < 2; ++mb) {
            #pragma unroll
            for (int r = 0; r < 16; ++r) {
                int m  = m0 + wm * 64 + mb * 32 + (r & 3) + 8 * (r >> 2) + 4 * hq;
                int b  = m >> 11, i = m & (L_ - 1);
                out[((size_t)(b * H_ + h) * L_ + i) * DH_ + dh] = f2bf((acc[mb][nb][r] + bb) * osc);
            }
        }
    }
#undef QKV_STAGE
}

// ---------------------------------------------------------------------------
// Kernel 2: column sums D_j = sum_i x_i*exp2(S'_ij). Wave owns 64 j
// (kf[2][4] in regs -> each Q-fragment read feeds 2 MFMA).
// ---------------------------------------------------------------------------
__global__ __launch_bounds__(256) void col_stats_mfma(
    const unsigned short* __restrict__ Qb, const unsigned short* __restrict__ Kb,
    const float* __restrict__ x, float* __restrict__ Do)
{
    __shared__ unsigned short Qlds[2][128 * 64];
    __shared__ float xlds[L_];

    const int t    = threadIdx.x;
    const int lane = t & 63;
    const int wv   = t >> 6;
    const int l31  = lane & 31;
    const int hq   = lane >> 5;
    const int bh   = blockIdx.y;
    const int b    = bh >> 4;
    const int j0   = blockIdx.x * 256 + wv * 64;

    const int srow0 = (lane >> 3);
    const int ssl   = lane & 7;

    #pragma unroll
    for (int u = 0; u < 2; ++u) {
        int f = t + 256 * u;
        *(float4*)&xlds[f * 4] = *(const float4*)&x[(size_t)b * L_ + f * 4];
    }

    short8v kf[2][4];
    #pragma unroll
    for (int s = 0; s < 2; ++s) {
        const unsigned short* kp = Kb + ((size_t)bh * L_ + j0 + s * 32 + l31) * DH_ + hq * 8;
        #pragma unroll
        for (int c = 0; c < 4; ++c) kf[s][c] = *(const short8v*)(kp + c * 16);
    }

    float d0[16], d1[16];
    #pragma unroll
    for (int r = 0; r < 16; ++r) { d0[r] = 0.f; d1[r] = 0.f; }

#define CS_STAGE(bb, ich)                                                           \
    {                                                                               \
        _Pragma("unroll")                                                           \
        for (int u = 0; u < 4; ++u) {                                               \
            int ch  = wv * 4 + u;                                                   \
            int row = ch * 8 + srow0;                                               \
            gl_lds16(&Qb[((size_t)bh * L_ + (ich) * 128 + row) * DH_ + ((ssl ^ (row & 7)) << 3)], \
                     &Qlds[bb][ch * 512]);                                          \
        }                                                                           \
    }

    CS_STAGE(0, 0);
    CS_STAGE(1, 1);
    __syncthreads();
    int cur = 0;

    const int NT = L_ / 128;         // 16
    for (int ich = 0; ich < NT; ++ich) {
        if (ich < NT - 1) WAITV(4); else WAITV(0);
        SBAR();
        #pragma unroll
        for (int cc = 0; cc < 4; ++cc) {
            f32x16 a0 = {}, a1 = {};
            __builtin_amdgcn_s_setprio(1);
            #pragma unroll
            for (int c = 0; c < 4; ++c) {
                int qr = cc * 32 + l31;
                short8v qv = *(const short8v*)&Qlds[cur][qr * 64 + (((c * 2 + hq) ^ (qr & 7)) << 3)];
                a0 = MFMA32(kf[0][c], qv, a0);
                a1 = MFMA32(kf[1][c], qv, a1);
            }
            __builtin_amdgcn_s_setprio(0);
            float xi = xlds[ich * 128 + cc * 32 + l31];
            #pragma unroll
            for (int r = 0; r < 16; ++r) {
                d0[r] += xi * __builtin_amdgcn_exp2f(a0[r]);
                d1[r] += xi * __builtin_amdgcn_exp2f(a1[r]);
            }
        }
        SBAR();
        if (ich + 2 < NT) CS_STAGE(cur, ich + 2);
        cur ^= 1;
    }

    #pragma unroll
    for (int r = 0; r < 16; ++r) {
        #pragma unroll
        for (int off = 16; off > 0; off >>= 1) {
            d0[r] += __shfl_xor(d0[r], off);
            d1[r] += __shfl_xor(d1[r], off);
        }
    }
    if (l31 == 0) {
        #pragma unroll
        for (int r = 0; r < 16; ++r) {
            int jr = 4 * hq + (r & 3) + 8 * (r >> 2);
            Do[(size_t)bh * L_ + j0 + jr]      = d0[r];
            Do[(size_t)bh * L_ + j0 + 32 + jr] = d1[r];
        }
    }
#undef CS_STAGE
}

// ---------------------------------------------------------------------------
// Kernel 3: Vt[bh][dh][j] = bf16( x_j * V[bh][j][dh] / D_j )
// ---------------------------------------------------------------------------
__global__ __launch_bounds__(256) void vt_prep(
    const unsigned short* __restrict__ Vb, const float* __restrict__ x,
    const float* __restrict__ Do, unsigned short* __restrict__ Vt)
{
    const int bh = blockIdx.y;
    const int b  = bh >> 4;
    const int j  = blockIdx.x * 256 + threadIdx.x;
    const float s = x[(size_t)b * L_ + j] / Do[(size_t)bh * L_ + j];
    const unsigned short* vp = Vb + ((size_t)bh * L_ + j) * DH_;
    #pragma unroll
    for (int c = 0; c < 16; ++c) {
        ushort4 v = *(const ushort4*)&vp[c * 4];
        Vt[((size_t)bh * DH_ + c * 4 + 0) * L_ + j] = f2bf(bf2f(v.x) * s);
        Vt[((size_t)bh * DH_ + c * 4 + 1) * L_ + j] = f2bf(bf2f(v.y) * s);
        Vt[((size_t)bh * DH_ + c * 4 + 2) * L_ + j] = f2bf(bf2f(v.z) * s);
        Vt[((size_t)bh * DH_ + c * 4 + 3) * L_ + j] = f2bf(bf2f(v.w) * s);
    }
}

// ---------------------------------------------------------------------------
// Kernel 4: attention output. P = exp2(S'), O = x_i * (P @ Vt^T).
// T12 in-register P; T4 counted-vmcnt 2-deep K/V pipeline. (unchanged)
// ---------------------------------------------------------------------------
__global__ __launch_bounds__(256) void attn_out_mfma(
    const unsigned short* __restrict__ Qb, const unsigned short* __restrict__ Kb,
    const unsigned short* __restrict__ Vt, const float* __restrict__ x,
    _Float16* __restrict__ Of)
{
    __shared__ unsigned short Klds[2][64 * 64];
    __shared__ unsigned short Vlds[2][64 * 64];

    const int t    = threadIdx.x;
    const int lane = t & 63;
    const int wv   = t >> 6;
    const int l31  = lane & 31;
    const int hq   = lane >> 5;
    const int bh   = blockIdx.y;
    const int b    = bh >> 4, hh = bh & 15;
    const int iw   = blockIdx.x * 128 + wv * 32;

    const int srow0 = (lane >> 3);
    const int ssl   = lane & 7;

    short8v qf[4];
    {
        const unsigned short* qp = Qb + ((size_t)bh * L_ + iw + l31) * DH_ + hq * 8;
        #pragma unroll
        for (int c = 0; c < 4; ++c) qf[c] = *(const short8v*)(qp + c * 16);
    }

    f32x16 accO0 = {}, accO1 = {};

#define AO_STAGE(bb, jt)                                                            \
    {                                                                               \
        _Pragma("unroll")                                                           \
        for (int u = 0; u < 2; ++u) {                                               \
            int ch  = wv * 2 + u;                                                   \
            int row = ch * 8 + srow0;                                               \
            gl_lds16(&Kb[((size_t)bh * L_ + (jt) * 64 + row) * DH_ + ((ssl ^ (row & 7)) << 3)], \
                     &Klds[bb][ch * 512]);                                          \
            gl_lds16(&Vt[((size_t)bh * DH_ + row) * L_ + (jt) * 64 + ((ssl ^ (row & 7)) << 3)], \
                     &Vlds[bb][ch * 512]);                                          \
        }                                                                           \
    }

    AO_STAGE(0, 0);
    AO_STAGE(1, 1);
    __syncthreads();
    int cur = 0;

    const int NT = L_ / 64;          // 32
    for (int jt = 0; jt < NT; ++jt) {
        if (jt < NT - 1) WAITV(4); else WAITV(0);
        SBAR();

        // ---- QK^T + in-register P->bf16 A-fragments (T12) ----
        uint4 pa[4];
        #pragma unroll
        for (int js = 0; js < 2; ++js) {
            f32x16 as = {};
            __builtin_amdgcn_s_setprio(1);
            #pragma unroll
            for (int c = 0; c < 4; ++c) {
                int krow = js * 32 + l31;
                short8v kfr = *(const short8v*)&Klds[cur][krow * 64 + (((c * 2 + hq) ^ (krow & 7)) << 3)];
                as = MFMA32(kfr, qf[c], as);
            }
            __builtin_amdgcn_s_setprio(0);
            float p[16];
            #pragma unroll
            for (int r = 0; r < 16; ++r) p[r] = __builtin_amdgcn_exp2f(as[r]);

            unsigned P0 = pack2_bf16(p[0], p[1]);
            unsigned P1 = pack2_bf16(p[2], p[3]);
            unsigned Q0 = pack2_bf16(p[4], p[5]);
            unsigned Q1 = pack2_bf16(p[6], p[7]);
            asm("v_permlane32_swap_b32 %0, %1" : "+v"(P0), "+v"(Q0));
            asm("v_permlane32_swap_b32 %0, %1" : "+v"(P1), "+v"(Q1));
            pa[js * 2 + 0] = make_uint4(P0, P1, Q0, Q1);

            unsigned R0 = pack2_bf16(p[8],  p[9]);
            unsigned R1 = pack2_bf16(p[10], p[11]);
            unsigned S0 = pack2_bf16(p[12], p[13]);
            unsigned S1 = pack2_bf16(p[14], p[15]);
            asm("v_permlane32_swap_b32 %0, %1" : "+v"(R0), "+v"(S0));
            asm("v_permlane32_swap_b32 %0, %1" : "+v"(R1), "+v"(S1));
            pa[js * 2 + 1] = make_uint4(R0, R1, S0, S1);
        }

        // ---- O += P · Vt^T ----
        __builtin_amdgcn_s_setprio(1);
        #pragma unroll
        for (int c = 0; c < 4; ++c) {
            union { uint4 u; short8v s; } paf; paf.u = pa[c];
            int r0 = l31, r1 = 32 + l31;
            short8v vf0 = *(const short8v*)&Vlds[cur][r0 * 64 + (((c * 2 + hq) ^ (r0 & 7)) << 3)];
            short8v vf1 = *(const short8v*)&Vlds[cur][r1 * 64 + (((c * 2 + hq) ^ (r1 & 7)) << 3)];
            accO0 = MFMA32(paf.s, vf0, accO0);
            accO1 = MFMA32(paf.s, vf1, accO1);
        }
        __builtin_amdgcn_s_setprio(0);
        SBAR();
        if (jt + 2 < NT) AO_STAGE(cur, jt + 2);
        cur ^= 1;
    }

    #pragma unroll
    for (int q = 0; q < 4; ++q) {
        float4 xq = *(const float4*)&x[(size_t)b * L_ + iw + 4 * hq + 8 * q];
        const float xs[4] = { xq.x, xq.y, xq.z, xq.w };
        #pragma unroll
        for (int k = 0; k < 4; ++k) {
            int r    = q * 4 + k;
            int irow = iw + 4 * hq + 8 * q + k;
            size_t base = ((size_t)b * L_ + irow) * E_ + hh * DH_;
            Of[base + l31]      = (_Float16)(accO0[r] * xs[k]);
            Of[base + 32 + l31] = (_Float16)(accO1[r] * xs[k]);
        }
    }
#undef AO_STAGE
}

// ---------------------------------------------------------------------------
// Kernel 5a: y_init — y[i] = b2[0].
// ---------------------------------------------------------------------------
__global__ __launch_bounds__(256) void y_init(float* __restrict__ y, const float* __restrict__ b2)
{
    y[blockIdx.x * 256 + threadIdx.x] = b2[0];
}

// ---------------------------------------------------------------------------
// Kernel 5b: fused MLP, fp16 MFMA. 256x256 tile, BK=64, 8 waves (2m x 4n),
// wave tile 128x64 (acc[4][2]) -> LDS reads 0.75 KB/MFMA (was 1.0).
// Counted-vmcnt 2-deep pipeline; 128 KB LDS; grid 16x16 (1 block/CU).
// ---------------------------------------------------------------------------
__global__ __launch_bounds__(512) void mlp_mfma(
    const _Float16* __restrict__ Of, const _Float16* __restrict__ W1t,
    const float* __restrict__ b1, const float* __restrict__ W2,
    float* __restrict__ y)
{
    __shared__ _Float16 Oh[2][256 * 64];
    __shared__ _Float16 Wh[2][256 * 64];

    const int t    = threadIdx.x;
    const int lane = t & 63;
    const int w    = t >> 6;
    const int l31  = lane & 31;
    const int hq   = lane >> 5;
    const int wm   = w >> 2, wn = w & 3;     // 2m x 4n
    const int m0   = blockIdx.x * 256;
    const int n0   = blockIdx.y * 256;

    const int srow0 = (lane >> 3);
    const int ssl   = lane & 7;

    f32x16 acc[4][2] = {};

#define MLP_STAGE(bb, kc)                                                          \
    {                                                                              \
        _Pragma("unroll")                                                          \
        for (int u = 0; u < 4; ++u) {                                              \
            int ch  = w * 4 + u;                                                   \
            int row = ch * 8 + srow0;                                              \
            gl_lds16(&Of[(size_t)(m0 + row) * E_ + (kc) * 64 + ((ssl ^ (row & 7)) << 3)], \
                     &Oh[bb][ch * 512]);                                           \
            gl_lds16(&W1t[(size_t)(n0 + row) * E_ + (kc) * 64 + ((ssl ^ (row & 7)) << 3)], \
                     &Wh[bb][ch * 512]);                                           \
        }                                                                          \
    }

    MLP_STAGE(0, 0);
    MLP_STAGE(1, 1);
    __syncthreads();
    int cur = 0;

    for (int kc = 0; kc < 16; ++kc) {
        if (kc < 15) WAITV(8); else WAITV(0);
        SBAR();
        __builtin_amdgcn_s_setprio(1);
        #pragma unroll
        for (int ks = 0; ks < 4; ++ks) {
            half8v fb[2];
            #pragma unroll
            for (int nb = 0; nb < 2; ++nb) {
                int br = wn * 64 + nb * 32 + l31;
                fb[nb] = *(const half8v*)&Wh[cur][br * 64 + (((ks * 2 + hq) ^ (br & 7)) << 3)];
            }
            #pragma unroll
            for (int mb = 0; mb < 4; ++mb) {
                int ar = wm * 128 + mb * 32 + l31;
                half8v fa = *(const half8v*)&Oh[cur][ar * 64 + (((ks * 2 + hq) ^ (ar & 7)) << 3)];
                acc[mb][0] = MFMAH(fa, fb[0], acc[mb][0]);
                acc[mb][1] = MFMAH(fa, fb[1], acc[mb][1]);
            }
        }
        __builtin_amdgcn_s_setprio(0);
        SBAR();
        if (kc + 2 < 16) MLP_STAGE(cur, kc + 2);
        cur ^= 1;
    }

    // epilogue: gelu + W2 dot; reduce over 32 lanes; atomicAdd per row.
    const int hid0 = n0 + wn * 64 + l31;
    const float bb0 = b1[hid0],      w20 = W2[hid0];
    const float bb1 = b1[hid0 + 32], w21 = W2[hid0 + 32];
    #pragma unroll
    for (int mb = 0; mb < 4; ++mb) {
        #pragma unroll
        for (int r = 0; r < 16; ++r) {
            float h0 = acc[mb][0][r] + bb0;
            float h1 = acc[mb][1][r] + bb1;
            float s  = 0.5f * h0 * (1.0f + erf_fast(h0 * 0.70710678f)) * w20
                     + 0.5f * h1 * (1.0f + erf_fast(h1 * 0.70710678f)) * w21;
            #pragma unroll
            for (int off = 16; off > 0; off >>= 1) s += __shfl_xor(s, off);
            if (l31 == 0) {
                int m = m0 + wm * 128 + mb * 32 + (r & 3) + 8 * (r >> 2) + 4 * hq;
                atomicAdd(&y[m], s);
            }
        }
    }
#undef MLP_STAGE
}

// ---------------------------------------------------------------------------
extern "C" void kernel_launch(void* const* d_in, const int* in_sizes, int n_in,
                              void* d_out, int out_size, void* d_ws, size_t ws_size,
                              hipStream_t stream)
{
    const float* x  = (const float*)d_in[0];
    const float* z  = (const float*)d_in[1];
    const float* Wq = (const float*)d_in[2];
    const float* bq = (const float*)d_in[3];
    const float* Wk = (const float*)d_in[4];
    const float* bk = (const float*)d_in[5];
    const float* Wv = (const float*)d_in[6];
    const float* bv = (const float*)d_in[7];
    const float* W1 = (const float*)d_in[8];
    const float* b1 = (const float*)d_in[9];
    const float* W2 = (const float*)d_in[10];
    const float* b2 = (const float*)d_in[11];
    float* y = (float*)d_out;

    const size_t NQ = (size_t)BH_ * L_ * DH_;        // 4.19M elems
    unsigned short* p = (unsigned short*)d_ws;
    unsigned short* Qb  = p;  p += NQ;               // Qb|Kb|Vb contiguous
    unsigned short* Kb  = p;  p += NQ;
    unsigned short* Vb  = p;  p += NQ;
    unsigned short* Vt  = p;  p += NQ;
    _Float16* zh  = (_Float16*)p;  p += (size_t)NROW_ * E_;
    _Float16* Tq  = (_Float16*)p;  p += (size_t)E_ * E_;   // Tq|Tk|Tv contiguous
    _Float16* Tk  = (_Float16*)p;  p += (size_t)E_ * E_;
    _Float16* Tv  = (_Float16*)p;  p += (size_t)E_ * E_;
    _Float16* W1t = (_Float16*)p;  p += (size_t)HID_ * E_;
    _Float16* Ofp = (_Float16*)p;  p += (size_t)NROW_ * E_;
    float* Dw = (float*)p;

    zh_prep<<<dim3((NROW_ * E_) / (256 * 8)), 256, 0, stream>>>(z, zh);
    wprep3 <<<dim3(E_ / 64, E_ / 64, 3), 256, 0, stream>>>(Wq, Wk, Wv, Tq, Tk, Tv);
    w1prep <<<dim3(HID_ / 64, E_ / 64), 256, 0, stream>>>(W1, W1t);

    qkv_mfma<<<dim3(NROW_ / 128, 3 * E_ / 128), 256, 0, stream>>>(
        zh, Tq, bq, bk, bv, Qb);

    col_stats_mfma<<<dim3(L_ / 256, BH_), 256, 0, stream>>>(Qb, Kb, x, Dw);

    vt_prep<<<dim3(L_ / 256, BH_), 256, 0, stream>>>(Vb, x, Dw, Vt);

    attn_out_mfma<<<dim3(L_ / 128, BH_), 256, 0, stream>>>(Qb, Kb, Vt, x, Ofp);

    y_init<<<dim3(NROW_ / 256), 256, 0, stream>>>(y, b2);

    mlp_mfma<<<dim3(NROW_ / 256, HID_ / 256), 512, 0, stream>>>(
        Ofp, W1t, b1, W2, y);
}

// Round 13
// 217.388 us; speedup vs baseline: 1.0204x; 1.0204x over previous
//
#include <hip/hip_runtime.h>
#include <hip/hip_bf16.h>
#include <math.h>

#define B_    2
#define L_    2048
#define E_    1024
#define H_    16
#define DH_   64
#define HID_  4096
#define NROW_ (B_*L_)   // 4096
#define BH_   (B_*H_)   // 32

// 0.125 (1/sqrt(DH)) * log2(e): Q pre-scale so P = exp2(S')
#define QSCL  0.18033688011112042f

typedef __attribute__((ext_vector_type(8)))  short    short8v;
typedef _Float16 half8v __attribute__((ext_vector_type(8)));
typedef __attribute__((ext_vector_type(16))) float    f32x16;

#define MFMA32(A, Bv, C) __builtin_amdgcn_mfma_f32_32x32x16_bf16((A), (Bv), (C), 0, 0, 0)
#define MFMAH(A, Bv, C)  __builtin_amdgcn_mfma_f32_32x32x16_f16((A), (Bv), (C), 0, 0, 0)

#define WAITV(N) asm volatile("s_waitcnt vmcnt(" #N ")" ::: "memory")
#define SBAR()   __builtin_amdgcn_s_barrier()

// float->bf16 round-half-up (2 ops).
__device__ __forceinline__ unsigned short f2bf(float f) {
    union { float f; unsigned u; } v; v.f = f;
    return (unsigned short)((v.u + 0x8000u) >> 16);
}
// pack two floats -> {bf16(hi), bf16(lo)} in 3 VALU ops via v_perm_b32
__device__ __forceinline__ unsigned pack2_bf16(float lo, float hi) {
    union { float f; unsigned u; } a, b; a.f = lo; b.f = hi;
    return __builtin_amdgcn_perm(b.u + 0x8000u, a.u + 0x8000u, 0x07060302u);
}
__device__ __forceinline__ float bf2f(unsigned short u) {
    union { unsigned u; float f; } v; v.u = ((unsigned)u) << 16;
    return v.f;
}

// async global->LDS, 16B per lane. Dest is wave-uniform base + lane*16.
__device__ __forceinline__ void gl_lds16(const void* g, void* l) {
    __builtin_amdgcn_global_load_lds(
        (const __attribute__((address_space(1))) unsigned int*)g,
        (__attribute__((address_space(3))) unsigned int*)l, 16, 0, 0);
}

// Abramowitz-Stegun 7.1.26, |abs err| < 1.5e-7
__device__ __forceinline__ float erf_fast(float v) {
    float a = fabsf(v);
    float t = __builtin_amdgcn_rcpf(1.0f + 0.3275911f * a);
    float p = t * (0.254829592f + t * (-0.284496736f + t * (1.421413741f +
              t * (-1.453152027f + t * 1.061405429f))));
    float r = 1.0f - p * __expf(-a * a);
    return copysignf(r, v);
}

// ---------------------------------------------------------------------------
// Prep A: cast z (fp32) -> zh (fp16), same layout.
// ---------------------------------------------------------------------------
__global__ __launch_bounds__(256) void zh_prep(
    const float* __restrict__ z, _Float16* __restrict__ zh)
{
    const size_t i = ((size_t)blockIdx.x * 256 + threadIdx.x) * 8;
    float4 a = *(const float4*)&z[i];
    float4 b = *(const float4*)&z[i + 4];
    union { _Float16 h[8]; half8v v; } o;
    o.h[0] = (_Float16)a.x; o.h[1] = (_Float16)a.y;
    o.h[2] = (_Float16)a.z; o.h[3] = (_Float16)a.w;
    o.h[4] = (_Float16)b.x; o.h[5] = (_Float16)b.y;
    o.h[6] = (_Float16)b.z; o.h[7] = (_Float16)b.w;
    *(half8v*)&zh[i] = o.v;
}

// ---------------------------------------------------------------------------
// Prep B: transpose+cast Wq/Wk/Wv (ExE fp32) -> T* (n-major fp16, contiguous
// so Tq base acts as a fused [3072][1024] weight).
// ---------------------------------------------------------------------------
__global__ __launch_bounds__(256) void wprep3(
    const float* __restrict__ Wq, const float* __restrict__ Wk,
    const float* __restrict__ Wv,
    _Float16* __restrict__ Tq, _Float16* __restrict__ Tk,
    _Float16* __restrict__ Tv)
{
    const float* src = (blockIdx.z == 0) ? Wq : (blockIdx.z == 1) ? Wk : Wv;
    _Float16*    dst = (blockIdx.z == 0) ? Tq : (blockIdx.z == 1) ? Tk : Tv;
    __shared__ float tile[64][65];
    const int t  = threadIdx.x;
    const int r0 = blockIdx.y * 64, c0 = blockIdx.x * 64;
    #pragma unroll
    for (int u = 0; u < 4; ++u) {
        int f = t + 256 * u, row = f >> 4, c4 = (f & 15) << 2;
        *(float4*)&tile[row][c4] = *(const float4*)&src[(size_t)(r0 + row) * E_ + c0 + c4];
    }
    __syncthreads();
    #pragma unroll
    for (int u = 0; u < 4; ++u) {
        int f = t + 256 * u, c = f >> 4, r4 = (f & 15) << 2;
        union { _Float16 h[4]; uint2 u2; } pk;
        pk.h[0] = (_Float16)tile[r4 + 0][c];
        pk.h[1] = (_Float16)tile[r4 + 1][c];
        pk.h[2] = (_Float16)tile[r4 + 2][c];
        pk.h[3] = (_Float16)tile[r4 + 3][c];
        *(uint2*)&dst[(size_t)(c0 + c) * E_ + r0 + r4] = pk.u2;
    }
}

// ---------------------------------------------------------------------------
// Prep C: transpose+cast W1 (E x HID fp32) -> W1t (HID x E fp16).
// ---------------------------------------------------------------------------
__global__ __launch_bounds__(256) void w1prep(
    const float* __restrict__ W1, _Float16* __restrict__ W1t)
{
    __shared__ float tile[64][65];
    const int t  = threadIdx.x;
    const int r0 = blockIdx.y * 64, c0 = blockIdx.x * 64;
    #pragma unroll
    for (int u = 0; u < 4; ++u) {
        int f = t + 256 * u, row = f >> 4, c4 = (f & 15) << 2;
        *(float4*)&tile[row][c4] = *(const float4*)&W1[(size_t)(r0 + row) * HID_ + c0 + c4];
    }
    __syncthreads();
    #pragma unroll
    for (int u = 0; u < 4; ++u) {
        int f = t + 256 * u, c = f >> 4, r4 = (f & 15) << 2;
        union { _Float16 h[4]; uint2 u2; } pk;
        pk.h[0] = (_Float16)tile[r4 + 0][c];
        pk.h[1] = (_Float16)tile[r4 + 1][c];
        pk.h[2] = (_Float16)tile[r4 + 2][c];
        pk.h[3] = (_Float16)tile[r4 + 3][c];
        *(uint2*)&W1t[(size_t)(c0 + c) * E_ + r0 + r4] = pk.u2;
    }
}

// ---------------------------------------------------------------------------
// Kernel 1: fused QKV projection (single dispatch over n=3072), fp16 MFMA,
// 128x128 tile, BK=64, 4 waves, counted-vmcnt 2-deep pipeline.
// ---------------------------------------------------------------------------
__global__ __launch_bounds__(256) void qkv_mfma(
    const _Float16* __restrict__ zh,
    const _Float16* __restrict__ Tall,      // fused [3072][1024]
    const float* __restrict__ bq, const float* __restrict__ bk,
    const float* __restrict__ bv,
    unsigned short* __restrict__ outQKV)    // Qb | Kb | Vb contiguous
{
    const int which = blockIdx.y >> 3;      // 1024/128 = 8 tiles per weight
    const float* bias = (which == 0) ? bq : (which == 1) ? bk : bv;
    const float  osc  = (which == 0) ? QSCL : 1.0f;
    unsigned short* out = outQKV + (size_t)which * ((size_t)BH_ * L_ * DH_);

    __shared__ _Float16 Ah[2][128 * 64];
    __shared__ _Float16 Bs[2][128 * 64];

    const int t    = threadIdx.x;
    const int lane = t & 63;
    const int w    = t >> 6;
    const int l31  = lane & 31;
    const int hq   = lane >> 5;
    const int wm   = w >> 1, wn = w & 1;
    const int m0   = blockIdx.x * 128;
    const int n0   = blockIdx.y * 128;      // global fused n

    const int srow0 = (lane >> 3);
    const int ssl   = lane & 7;

    f32x16 acc[2][2] = {};

#define QKV_STAGE(bb, kc)                                                          \
    {                                                                              \
        _Pragma("unroll")                                                          \
        for (int u = 0; u < 4; ++u) {                                              \
            int ch  = w * 4 + u;                                                   \
            int row = ch * 8 + srow0;                                              \
            gl_lds16(&zh[(size_t)(m0 + row) * E_ + (kc) * 64 + ((ssl ^ (row & 7)) << 3)], \
                     &Ah[bb][ch * 512]);                                           \
            gl_lds16(&Tall[(size_t)(n0 + row) * E_ + (kc) * 64 + ((ssl ^ (row & 7)) << 3)], \
                     &Bs[bb][ch * 512]);                                           \
        }                                                                          \
    }

    QKV_STAGE(0, 0);
    QKV_STAGE(1, 1);
    __syncthreads();
    int cur = 0;

    for (int kc = 0; kc < 16; ++kc) {
        if (kc < 15) WAITV(8); else WAITV(0);
        SBAR();
        __builtin_amdgcn_s_setprio(1);
        #pragma unroll
        for (int ks = 0; ks < 4; ++ks) {
            half8v fb[2];
            #pragma unroll
            for (int nb = 0; nb < 2; ++nb) {
                int br = wn * 64 + nb * 32 + l31;
                fb[nb] = *(const half8v*)&Bs[cur][br * 64 + (((ks * 2 + hq) ^ (br & 7)) << 3)];
            }
            #pragma unroll
            for (int mb = 0; mb < 2; ++mb) {
                int ar = wm * 64 + mb * 32 + l31;
                half8v fa = *(const half8v*)&Ah[cur][ar * 64 + (((ks * 2 + hq) ^ (ar & 7)) << 3)];
                acc[mb][0] = MFMAH(fa, fb[0], acc[mb][0]);
                acc[mb][1] = MFMAH(fa, fb[1], acc[mb][1]);
            }
        }
        __builtin_amdgcn_s_setprio(0);
        SBAR();
        if (kc + 2 < 16) QKV_STAGE(cur, kc + 2);
        cur ^= 1;
    }

    // epilogue: bias (+ Q scale) + bf16 scatter to (BH,L,DH)
    #pragma unroll
    for (int nb = 0; nb < 2; ++nb) {
        int n  = n0 + wn * 64 + nb * 32 + l31;   // fused n
        int nn = n & 1023;
        int h  = nn >> 6, dh = nn & 63;
        float bb = bias[nn];
        #pragma unroll
        for (int mb = 0; mb < 2; ++mb) {
            #pragma unroll
            for (int r = 0; r < 16; ++r) {
                int m  = m0 + wm * 64 + mb * 32 + (r & 3) + 8 * (r >> 2) + 4 * hq;
                int b  = m >> 11, i = m & (L_ - 1);
                out[((size_t)(b * H_ + h) * L_ + i) * DH_ + dh] = f2bf((acc[mb][nb][r] + bb) * osc);
            }
        }
    }
#undef QKV_STAGE
}

// ---------------------------------------------------------------------------
// Kernel 2: column sums D_j = sum_i x_i*exp2(S'_ij). Wave owns 64 j
// (kf[2][4] in regs -> each Q-fragment read feeds 2 MFMA).
// ---------------------------------------------------------------------------
__global__ __launch_bounds__(256) void col_stats_mfma(
    const unsigned short* __restrict__ Qb, const unsigned short* __restrict__ Kb,
    const float* __restrict__ x, float* __restrict__ Do)
{
    __shared__ unsigned short Qlds[2][128 * 64];
    __shared__ float xlds[L_];

    const int t    = threadIdx.x;
    const int lane = t & 63;
    const int wv   = t >> 6;
    const int l31  = lane & 31;
    const int hq   = lane >> 5;
    const int bh   = blockIdx.y;
    const int b    = bh >> 4;
    const int j0   = blockIdx.x * 256 + wv * 64;

    const int srow0 = (lane >> 3);
    const int ssl   = lane & 7;

    #pragma unroll
    for (int u = 0; u < 2; ++u) {
        int f = t + 256 * u;
        *(float4*)&xlds[f * 4] = *(const float4*)&x[(size_t)b * L_ + f * 4];
    }

    short8v kf[2][4];
    #pragma unroll
    for (int s = 0; s < 2; ++s) {
        const unsigned short* kp = Kb + ((size_t)bh * L_ + j0 + s * 32 + l31) * DH_ + hq * 8;
        #pragma unroll
        for (int c = 0; c < 4; ++c) kf[s][c] = *(const short8v*)(kp + c * 16);
    }

    float d0[16], d1[16];
    #pragma unroll
    for (int r = 0; r < 16; ++r) { d0[r] = 0.f; d1[r] = 0.f; }

#define CS_STAGE(bb, ich)                                                           \
    {                                                                               \
        _Pragma("unroll")                                                           \
        for (int u = 0; u < 4; ++u) {                                               \
            int ch  = wv * 4 + u;                                                   \
            int row = ch * 8 + srow0;                                               \
            gl_lds16(&Qb[((size_t)bh * L_ + (ich) * 128 + row) * DH_ + ((ssl ^ (row & 7)) << 3)], \
                     &Qlds[bb][ch * 512]);                                          \
        }                                                                           \
    }

    CS_STAGE(0, 0);
    CS_STAGE(1, 1);
    __syncthreads();
    int cur = 0;

    const int NT = L_ / 128;         // 16
    for (int ich = 0; ich < NT; ++ich) {
        if (ich < NT - 1) WAITV(4); else WAITV(0);
        SBAR();
        #pragma unroll
        for (int cc = 0; cc < 4; ++cc) {
            f32x16 a0 = {}, a1 = {};
            __builtin_amdgcn_s_setprio(1);
            #pragma unroll
            for (int c = 0; c < 4; ++c) {
                int qr = cc * 32 + l31;
                short8v qv = *(const short8v*)&Qlds[cur][qr * 64 + (((c * 2 + hq) ^ (qr & 7)) << 3)];
                a0 = MFMA32(kf[0][c], qv, a0);
                a1 = MFMA32(kf[1][c], qv, a1);
            }
            __builtin_amdgcn_s_setprio(0);
            float xi = xlds[ich * 128 + cc * 32 + l31];
            #pragma unroll
            for (int r = 0; r < 16; ++r) {
                d0[r] += xi * __builtin_amdgcn_exp2f(a0[r]);
                d1[r] += xi * __builtin_amdgcn_exp2f(a1[r]);
            }
        }
        SBAR();
        if (ich + 2 < NT) CS_STAGE(cur, ich + 2);
        cur ^= 1;
    }

    #pragma unroll
    for (int r = 0; r < 16; ++r) {
        #pragma unroll
        for (int off = 16; off > 0; off >>= 1) {
            d0[r] += __shfl_xor(d0[r], off);
            d1[r] += __shfl_xor(d1[r], off);
        }
    }
    if (l31 == 0) {
        #pragma unroll
        for (int r = 0; r < 16; ++r) {
            int jr = 4 * hq + (r & 3) + 8 * (r >> 2);
            Do[(size_t)bh * L_ + j0 + jr]      = d0[r];
            Do[(size_t)bh * L_ + j0 + 32 + jr] = d1[r];
        }
    }
#undef CS_STAGE
}

// ---------------------------------------------------------------------------
// Kernel 3: Vt[bh][dh][j] = bf16( x_j * V[bh][j][dh] / D_j )
// ---------------------------------------------------------------------------
__global__ __launch_bounds__(256) void vt_prep(
    const unsigned short* __restrict__ Vb, const float* __restrict__ x,
    const float* __restrict__ Do, unsigned short* __restrict__ Vt)
{
    const int bh = blockIdx.y;
    const int b  = bh >> 4;
    const int j  = blockIdx.x * 256 + threadIdx.x;
    const float s = x[(size_t)b * L_ + j] / Do[(size_t)bh * L_ + j];
    const unsigned short* vp = Vb + ((size_t)bh * L_ + j) * DH_;
    #pragma unroll
    for (int c = 0; c < 16; ++c) {
        ushort4 v = *(const ushort4*)&vp[c * 4];
        Vt[((size_t)bh * DH_ + c * 4 + 0) * L_ + j] = f2bf(bf2f(v.x) * s);
        Vt[((size_t)bh * DH_ + c * 4 + 1) * L_ + j] = f2bf(bf2f(v.y) * s);
        Vt[((size_t)bh * DH_ + c * 4 + 2) * L_ + j] = f2bf(bf2f(v.z) * s);
        Vt[((size_t)bh * DH_ + c * 4 + 3) * L_ + j] = f2bf(bf2f(v.w) * s);
    }
}

// ---------------------------------------------------------------------------
// Kernel 4: attention output. P = exp2(S'), O = x_i * (P @ Vt^T).
// Wave owns 64 i (qf[2][4] in regs): each K/V-fragment LDS read feeds 2 MFMA
// (reads/MFMA 1.0 -> 0.5). Block = 4 waves x 64 i = 256 i. T12 in-register P;
// counted-vmcnt 2-deep K/V pipeline.
// ---------------------------------------------------------------------------
__global__ __launch_bounds__(256) void attn_out_mfma(
    const unsigned short* __restrict__ Qb, const unsigned short* __restrict__ Kb,
    const unsigned short* __restrict__ Vt, const float* __restrict__ x,
    _Float16* __restrict__ Of)
{
    __shared__ unsigned short Klds[2][64 * 64];
    __shared__ unsigned short Vlds[2][64 * 64];

    const int t    = threadIdx.x;
    const int lane = t & 63;
    const int wv   = t >> 6;
    const int l31  = lane & 31;
    const int hq   = lane >> 5;
    const int bh   = blockIdx.y;
    const int b    = bh >> 4, hh = bh & 15;
    const int iw   = blockIdx.x * 256 + wv * 64;

    const int srow0 = (lane >> 3);
    const int ssl   = lane & 7;

    short8v qf[2][4];
    #pragma unroll
    for (int ig = 0; ig < 2; ++ig) {
        const unsigned short* qp = Qb + ((size_t)bh * L_ + iw + ig * 32 + l31) * DH_ + hq * 8;
        #pragma unroll
        for (int c = 0; c < 4; ++c) qf[ig][c] = *(const short8v*)(qp + c * 16);
    }

    f32x16 accO[2][2] = {};   // [igroup][jhalf of dh]

#define AO_STAGE(bb, jt)                                                            \
    {                                                                               \
        _Pragma("unroll")                                                           \
        for (int u = 0; u < 2; ++u) {                                               \
            int ch  = wv * 2 + u;                                                   \
            int row = ch * 8 + srow0;                                               \
            gl_lds16(&Kb[((size_t)bh * L_ + (jt) * 64 + row) * DH_ + ((ssl ^ (row & 7)) << 3)], \
                     &Klds[bb][ch * 512]);                                          \
            gl_lds16(&Vt[((size_t)bh * DH_ + row) * L_ + (jt) * 64 + ((ssl ^ (row & 7)) << 3)], \
                     &Vlds[bb][ch * 512]);                                          \
        }                                                                           \
    }

    AO_STAGE(0, 0);
    AO_STAGE(1, 1);
    __syncthreads();
    int cur = 0;

    const int NT = L_ / 64;          // 32
    for (int jt = 0; jt < NT; ++jt) {
        if (jt < NT - 1) WAITV(4); else WAITV(0);
        SBAR();

        // ---- QK^T (two i-groups share each K-fragment) + T12 P packing ----
        uint4 pa[2][4];
        #pragma unroll
        for (int js = 0; js < 2; ++js) {
            f32x16 as0 = {}, as1 = {};
            __builtin_amdgcn_s_setprio(1);
            #pragma unroll
            for (int c = 0; c < 4; ++c) {
                int krow = js * 32 + l31;
                short8v kfr = *(const short8v*)&Klds[cur][krow * 64 + (((c * 2 + hq) ^ (krow & 7)) << 3)];
                as0 = MFMA32(kfr, qf[0][c], as0);
                as1 = MFMA32(kfr, qf[1][c], as1);
            }
            __builtin_amdgcn_s_setprio(0);
            #pragma unroll
            for (int ig = 0; ig < 2; ++ig) {
                const f32x16& as = (ig == 0) ? as0 : as1;
                float p[16];
                #pragma unroll
                for (int r = 0; r < 16; ++r) p[r] = __builtin_amdgcn_exp2f(as[r]);

                unsigned P0 = pack2_bf16(p[0], p[1]);
                unsigned P1 = pack2_bf16(p[2], p[3]);
                unsigned Q0 = pack2_bf16(p[4], p[5]);
                unsigned Q1 = pack2_bf16(p[6], p[7]);
                asm("v_permlane32_swap_b32 %0, %1" : "+v"(P0), "+v"(Q0));
                asm("v_permlane32_swap_b32 %0, %1" : "+v"(P1), "+v"(Q1));
                pa[ig][js * 2 + 0] = make_uint4(P0, P1, Q0, Q1);

                unsigned R0 = pack2_bf16(p[8],  p[9]);
                unsigned R1 = pack2_bf16(p[10], p[11]);
                unsigned S0 = pack2_bf16(p[12], p[13]);
                unsigned S1 = pack2_bf16(p[14], p[15]);
                asm("v_permlane32_swap_b32 %0, %1" : "+v"(R0), "+v"(S0));
                asm("v_permlane32_swap_b32 %0, %1" : "+v"(R1), "+v"(S1));
                pa[ig][js * 2 + 1] = make_uint4(R0, R1, S0, S1);
            }
        }

        // ---- O += P · Vt^T (two i-groups share each V-fragment) ----
        __builtin_amdgcn_s_setprio(1);
        #pragma unroll
        for (int c = 0; c < 4; ++c) {
            union { uint4 u; short8v s; } pa0, pa1;
            pa0.u = pa[0][c]; pa1.u = pa[1][c];
            int r0 = l31, r1 = 32 + l31;
            short8v vf0 = *(const short8v*)&Vlds[cur][r0 * 64 + (((c * 2 + hq) ^ (r0 & 7)) << 3)];
            short8v vf1 = *(const short8v*)&Vlds[cur][r1 * 64 + (((c * 2 + hq) ^ (r1 & 7)) << 3)];
            accO[0][0] = MFMA32(pa0.s, vf0, accO[0][0]);
            accO[0][1] = MFMA32(pa0.s, vf1, accO[0][1]);
            accO[1][0] = MFMA32(pa1.s, vf0, accO[1][0]);
            accO[1][1] = MFMA32(pa1.s, vf1, accO[1][1]);
        }
        __builtin_amdgcn_s_setprio(0);
        SBAR();
        if (jt + 2 < NT) AO_STAGE(cur, jt + 2);
        cur ^= 1;
    }

    #pragma unroll
    for (int ig = 0; ig < 2; ++ig) {
        #pragma unroll
        for (int q = 0; q < 4; ++q) {
            float4 xq = *(const float4*)&x[(size_t)b * L_ + iw + ig * 32 + 4 * hq + 8 * q];
            const float xs[4] = { xq.x, xq.y, xq.z, xq.w };
            #pragma unroll
            for (int k = 0; k < 4; ++k) {
                int r    = q * 4 + k;
                int irow = iw + ig * 32 + 4 * hq + 8 * q + k;
                size_t base = ((size_t)b * L_ + irow) * E_ + hh * DH_;
                Of[base + l31]      = (_Float16)(accO[ig][0][r] * xs[k]);
                Of[base + 32 + l31] = (_Float16)(accO[ig][1][r] * xs[k]);
            }
        }
    }
#undef AO_STAGE
}

// ---------------------------------------------------------------------------
// Kernel 5a: y_init — y[i] = b2[0].
// ---------------------------------------------------------------------------
__global__ __launch_bounds__(256) void y_init(float* __restrict__ y, const float* __restrict__ b2)
{
    y[blockIdx.x * 256 + threadIdx.x] = b2[0];
}

// ---------------------------------------------------------------------------
// Kernel 5b: fused MLP, fp16 MFMA, 128x128, BK=64, counted-vmcnt pipeline.
// (R11-proven version: 63.5 us)
// ---------------------------------------------------------------------------
__global__ __launch_bounds__(256) void mlp_mfma(
    const _Float16* __restrict__ Of, const _Float16* __restrict__ W1t,
    const float* __restrict__ b1, const float* __restrict__ W2,
    float* __restrict__ y)
{
    __shared__ _Float16 Oh[2][128 * 64];
    __shared__ _Float16 Wh[2][128 * 64];

    const int t    = threadIdx.x;
    const int lane = t & 63;
    const int w    = t >> 6;
    const int l31  = lane & 31;
    const int hq   = lane >> 5;
    const int wm   = w >> 1, wn = w & 1;
    const int m0   = blockIdx.x * 128;
    const int n0   = blockIdx.y * 128;

    const int srow0 = (lane >> 3);
    const int ssl   = lane & 7;

    f32x16 acc[2][2] = {};

#define MLP_STAGE(bb, kc)                                                          \
    {                                                                              \
        _Pragma("unroll")                                                          \
        for (int u = 0; u < 4; ++u) {                                              \
            int ch  = w * 4 + u;                                                   \
            int row = ch * 8 + srow0;                                              \
            gl_lds16(&Of[(size_t)(m0 + row) * E_ + (kc) * 64 + ((ssl ^ (row & 7)) << 3)], \
                     &Oh[bb][ch * 512]);                                           \
            gl_lds16(&W1t[(size_t)(n0 + row) * E_ + (kc) * 64 + ((ssl ^ (row & 7)) << 3)], \
                     &Wh[bb][ch * 512]);                                           \
        }                                                                          \
    }

    MLP_STAGE(0, 0);
    MLP_STAGE(1, 1);
    __syncthreads();
    int cur = 0;

    for (int kc = 0; kc < 16; ++kc) {
        if (kc < 15) WAITV(8); else WAITV(0);
        SBAR();
        __builtin_amdgcn_s_setprio(1);
        #pragma unroll
        for (int ks = 0; ks < 4; ++ks) {
            half8v fb[2];
            #pragma unroll
            for (int nb = 0; nb < 2; ++nb) {
                int br = wn * 64 + nb * 32 + l31;
                fb[nb] = *(const half8v*)&Wh[cur][br * 64 + (((ks * 2 + hq) ^ (br & 7)) << 3)];
            }
            #pragma unroll
            for (int mb = 0; mb < 2; ++mb) {
                int ar = wm * 64 + mb * 32 + l31;
                half8v fa = *(const half8v*)&Oh[cur][ar * 64 + (((ks * 2 + hq) ^ (ar & 7)) << 3)];
                acc[mb][0] = MFMAH(fa, fb[0], acc[mb][0]);
                acc[mb][1] = MFMAH(fa, fb[1], acc[mb][1]);
            }
        }
        __builtin_amdgcn_s_setprio(0);
        SBAR();
        if (kc + 2 < 16) MLP_STAGE(cur, kc + 2);
        cur ^= 1;
    }

    // epilogue: gelu + W2 dot; reduce over 32 lanes; atomicAdd per row.
    const int hid0 = n0 + wn * 64 + l31;
    const float bb0 = b1[hid0],      w20 = W2[hid0];
    const float bb1 = b1[hid0 + 32], w21 = W2[hid0 + 32];
    #pragma unroll
    for (int mb = 0; mb < 2; ++mb) {
        #pragma unroll
        for (int r = 0; r < 16; ++r) {
            float h0 = acc[mb][0][r] + bb0;
            float h1 = acc[mb][1][r] + bb1;
            float s  = 0.5f * h0 * (1.0f + erf_fast(h0 * 0.70710678f)) * w20
                     + 0.5f * h1 * (1.0f + erf_fast(h1 * 0.70710678f)) * w21;
            #pragma unroll
            for (int off = 16; off > 0; off >>= 1) s += __shfl_xor(s, off);
            if (l31 == 0) {
                int m = m0 + wm * 64 + mb * 32 + (r & 3) + 8 * (r >> 2) + 4 * hq;
                atomicAdd(&y[m], s);
            }
        }
    }
#undef MLP_STAGE
}

// ---------------------------------------------------------------------------
extern "C" void kernel_launch(void* const* d_in, const int* in_sizes, int n_in,
                              void* d_out, int out_size, void* d_ws, size_t ws_size,
                              hipStream_t stream)
{
    const float* x  = (const float*)d_in[0];
    const float* z  = (const float*)d_in[1];
    const float* Wq = (const float*)d_in[2];
    const float* bq = (const float*)d_in[3];
    const float* Wk = (const float*)d_in[4];
    const float* bk = (const float*)d_in[5];
    const float* Wv = (const float*)d_in[6];
    const float* bv = (const float*)d_in[7];
    const float* W1 = (const float*)d_in[8];
    const float* b1 = (const float*)d_in[9];
    const float* W2 = (const float*)d_in[10];
    const float* b2 = (const float*)d_in[11];
    float* y = (float*)d_out;

    const size_t NQ = (size_t)BH_ * L_ * DH_;        // 4.19M elems
    unsigned short* p = (unsigned short*)d_ws;
    unsigned short* Qb  = p;  p += NQ;               // Qb|Kb|Vb contiguous
    unsigned short* Kb  = p;  p += NQ;
    unsigned short* Vb  = p;  p += NQ;
    unsigned short* Vt  = p;  p += NQ;
    _Float16* zh  = (_Float16*)p;  p += (size_t)NROW_ * E_;
    _Float16* Tq  = (_Float16*)p;  p += (size_t)E_ * E_;   // Tq|Tk|Tv contiguous
    _Float16* Tk  = (_Float16*)p;  p += (size_t)E_ * E_;
    _Float16* Tv  = (_Float16*)p;  p += (size_t)E_ * E_;
    _Float16* W1t = (_Float16*)p;  p += (size_t)HID_ * E_;
    _Float16* Ofp = (_Float16*)p;  p += (size_t)NROW_ * E_;
    float* Dw = (float*)p;

    zh_prep<<<dim3((NROW_ * E_) / (256 * 8)), 256, 0, stream>>>(z, zh);
    wprep3 <<<dim3(E_ / 64, E_ / 64, 3), 256, 0, stream>>>(Wq, Wk, Wv, Tq, Tk, Tv);
    w1prep <<<dim3(HID_ / 64, E_ / 64), 256, 0, stream>>>(W1, W1t);

    qkv_mfma<<<dim3(NROW_ / 128, 3 * E_ / 128), 256, 0, stream>>>(
        zh, Tq, bq, bk, bv, Qb);

    col_stats_mfma<<<dim3(L_ / 256, BH_), 256, 0, stream>>>(Qb, Kb, x, Dw);

    vt_prep<<<dim3(L_ / 256, BH_), 256, 0, stream>>>(Vb, x, Dw, Vt);

    attn_out_mfma<<<dim3(L_ / 256, BH_), 256, 0, stream>>>(Qb, Kb, Vt, x, Ofp);

    y_init<<<dim3(NROW_ / 256), 256, 0, stream>>>(y, b2);

    mlp_mfma<<<dim3(NROW_ / 128, HID_ / 128), 256, 0, stream>>>(
        Ofp, W1t, b1, W2, y);
}

// Round 14
// 207.116 us; speedup vs baseline: 1.0711x; 1.0496x over previous
//
#include <hip/hip_runtime.h>
#include <hip/hip_bf16.h>
#include <math.h>

#define B_    2
#define L_    2048
#define E_    1024
#define H_    16
#define DH_   64
#define HID_  4096
#define NROW_ (B_*L_)   // 4096
#define BH_   (B_*H_)   // 32

// 0.125 (1/sqrt(DH)) * log2(e): Q pre-scale so P = exp2(S')
#define QSCL  0.18033688011112042f

typedef __attribute__((ext_vector_type(8)))  short    short8v;
typedef _Float16 half8v __attribute__((ext_vector_type(8)));
typedef __attribute__((ext_vector_type(16))) float    f32x16;

#define MFMA32(A, Bv, C) __builtin_amdgcn_mfma_f32_32x32x16_bf16((A), (Bv), (C), 0, 0, 0)
#define MFMAH(A, Bv, C)  __builtin_amdgcn_mfma_f32_32x32x16_f16((A), (Bv), (C), 0, 0, 0)

#define WAITV(N) asm volatile("s_waitcnt vmcnt(" #N ")" ::: "memory")
#define SBAR()   __builtin_amdgcn_s_barrier()

// float->bf16 round-half-up (2 ops).
__device__ __forceinline__ unsigned short f2bf(float f) {
    union { float f; unsigned u; } v; v.f = f;
    return (unsigned short)((v.u + 0x8000u) >> 16);
}
// pack two floats -> {bf16(hi), bf16(lo)} in 3 VALU ops via v_perm_b32
__device__ __forceinline__ unsigned pack2_bf16(float lo, float hi) {
    union { float f; unsigned u; } a, b; a.f = lo; b.f = hi;
    return __builtin_amdgcn_perm(b.u + 0x8000u, a.u + 0x8000u, 0x07060302u);
}
__device__ __forceinline__ float bf2f(unsigned short u) {
    union { unsigned u; float f; } v; v.u = ((unsigned)u) << 16;
    return v.f;
}

// async global->LDS, 16B per lane. Dest is wave-uniform base + lane*16.
__device__ __forceinline__ void gl_lds16(const void* g, void* l) {
    __builtin_amdgcn_global_load_lds(
        (const __attribute__((address_space(1))) unsigned int*)g,
        (__attribute__((address_space(3))) unsigned int*)l, 16, 0, 0);
}

// Abramowitz-Stegun 7.1.26, |abs err| < 1.5e-7
__device__ __forceinline__ float erf_fast(float v) {
    float a = fabsf(v);
    float t = __builtin_amdgcn_rcpf(1.0f + 0.3275911f * a);
    float p = t * (0.254829592f + t * (-0.284496736f + t * (1.421413741f +
              t * (-1.453152027f + t * 1.061405429f))));
    float r = 1.0f - p * __expf(-a * a);
    return copysignf(r, v);
}

// ---------------------------------------------------------------------------
// Prep A: cast z (fp32) -> zh (fp16), same layout.
// ---------------------------------------------------------------------------
__global__ __launch_bounds__(256) void zh_prep(
    const float* __restrict__ z, _Float16* __restrict__ zh)
{
    const size_t i = ((size_t)blockIdx.x * 256 + threadIdx.x) * 8;
    float4 a = *(const float4*)&z[i];
    float4 b = *(const float4*)&z[i + 4];
    union { _Float16 h[8]; half8v v; } o;
    o.h[0] = (_Float16)a.x; o.h[1] = (_Float16)a.y;
    o.h[2] = (_Float16)a.z; o.h[3] = (_Float16)a.w;
    o.h[4] = (_Float16)b.x; o.h[5] = (_Float16)b.y;
    o.h[6] = (_Float16)b.z; o.h[7] = (_Float16)b.w;
    *(half8v*)&zh[i] = o.v;
}

// ---------------------------------------------------------------------------
// Prep B: transpose+cast Wq/Wk/Wv (ExE fp32) -> T* (n-major fp16, contiguous
// so Tq base acts as a fused [3072][1024] weight).
// ---------------------------------------------------------------------------
__global__ __launch_bounds__(256) void wprep3(
    const float* __restrict__ Wq, const float* __restrict__ Wk,
    const float* __restrict__ Wv,
    _Float16* __restrict__ Tq, _Float16* __restrict__ Tk,
    _Float16* __restrict__ Tv)
{
    const float* src = (blockIdx.z == 0) ? Wq : (blockIdx.z == 1) ? Wk : Wv;
    _Float16*    dst = (blockIdx.z == 0) ? Tq : (blockIdx.z == 1) ? Tk : Tv;
    __shared__ float tile[64][65];
    const int t  = threadIdx.x;
    const int r0 = blockIdx.y * 64, c0 = blockIdx.x * 64;
    #pragma unroll
    for (int u = 0; u < 4; ++u) {
        int f = t + 256 * u, row = f >> 4, c4 = (f & 15) << 2;
        *(float4*)&tile[row][c4] = *(const float4*)&src[(size_t)(r0 + row) * E_ + c0 + c4];
    }
    __syncthreads();
    #pragma unroll
    for (int u = 0; u < 4; ++u) {
        int f = t + 256 * u, c = f >> 4, r4 = (f & 15) << 2;
        union { _Float16 h[4]; uint2 u2; } pk;
        pk.h[0] = (_Float16)tile[r4 + 0][c];
        pk.h[1] = (_Float16)tile[r4 + 1][c];
        pk.h[2] = (_Float16)tile[r4 + 2][c];
        pk.h[3] = (_Float16)tile[r4 + 3][c];
        *(uint2*)&dst[(size_t)(c0 + c) * E_ + r0 + r4] = pk.u2;
    }
}

// ---------------------------------------------------------------------------
// Prep C: transpose+cast W1 (E x HID fp32) -> W1t (HID x E fp16).
// ---------------------------------------------------------------------------
__global__ __launch_bounds__(256) void w1prep(
    const float* __restrict__ W1, _Float16* __restrict__ W1t)
{
    __shared__ float tile[64][65];
    const int t  = threadIdx.x;
    const int r0 = blockIdx.y * 64, c0 = blockIdx.x * 64;
    #pragma unroll
    for (int u = 0; u < 4; ++u) {
        int f = t + 256 * u, row = f >> 4, c4 = (f & 15) << 2;
        *(float4*)&tile[row][c4] = *(const float4*)&W1[(size_t)(r0 + row) * HID_ + c0 + c4];
    }
    __syncthreads();
    #pragma unroll
    for (int u = 0; u < 4; ++u) {
        int f = t + 256 * u, c = f >> 4, r4 = (f & 15) << 2;
        union { _Float16 h[4]; uint2 u2; } pk;
        pk.h[0] = (_Float16)tile[r4 + 0][c];
        pk.h[1] = (_Float16)tile[r4 + 1][c];
        pk.h[2] = (_Float16)tile[r4 + 2][c];
        pk.h[3] = (_Float16)tile[r4 + 3][c];
        *(uint2*)&W1t[(size_t)(c0 + c) * E_ + r0 + r4] = pk.u2;
    }
}

// ---------------------------------------------------------------------------
// Kernel 1: fused QKV projection (single dispatch over n=3072), fp16 MFMA,
// 128x128 tile, BK=64, 4 waves, counted-vmcnt 2-deep pipeline.
// ---------------------------------------------------------------------------
__global__ __launch_bounds__(256) void qkv_mfma(
    const _Float16* __restrict__ zh,
    const _Float16* __restrict__ Tall,      // fused [3072][1024]
    const float* __restrict__ bq, const float* __restrict__ bk,
    const float* __restrict__ bv,
    unsigned short* __restrict__ outQKV)    // Qb | Kb | Vb contiguous
{
    const int which = blockIdx.y >> 3;      // 1024/128 = 8 tiles per weight
    const float* bias = (which == 0) ? bq : (which == 1) ? bk : bv;
    const float  osc  = (which == 0) ? QSCL : 1.0f;
    unsigned short* out = outQKV + (size_t)which * ((size_t)BH_ * L_ * DH_);

    __shared__ _Float16 Ah[2][128 * 64];
    __shared__ _Float16 Bs[2][128 * 64];

    const int t    = threadIdx.x;
    const int lane = t & 63;
    const int w    = t >> 6;
    const int l31  = lane & 31;
    const int hq   = lane >> 5;
    const int wm   = w >> 1, wn = w & 1;
    const int m0   = blockIdx.x * 128;
    const int n0   = blockIdx.y * 128;      // global fused n

    const int srow0 = (lane >> 3);
    const int ssl   = lane & 7;

    f32x16 acc[2][2] = {};

#define QKV_STAGE(bb, kc)                                                          \
    {                                                                              \
        _Pragma("unroll")                                                          \
        for (int u = 0; u < 4; ++u) {                                              \
            int ch  = w * 4 + u;                                                   \
            int row = ch * 8 + srow0;                                              \
            gl_lds16(&zh[(size_t)(m0 + row) * E_ + (kc) * 64 + ((ssl ^ (row & 7)) << 3)], \
                     &Ah[bb][ch * 512]);                                           \
            gl_lds16(&Tall[(size_t)(n0 + row) * E_ + (kc) * 64 + ((ssl ^ (row & 7)) << 3)], \
                     &Bs[bb][ch * 512]);                                           \
        }                                                                          \
    }

    QKV_STAGE(0, 0);
    QKV_STAGE(1, 1);
    __syncthreads();
    int cur = 0;

    for (int kc = 0; kc < 16; ++kc) {
        if (kc < 15) WAITV(8); else WAITV(0);
        SBAR();
        __builtin_amdgcn_s_setprio(1);
        #pragma unroll
        for (int ks = 0; ks < 4; ++ks) {
            half8v fb[2];
            #pragma unroll
            for (int nb = 0; nb < 2; ++nb) {
                int br = wn * 64 + nb * 32 + l31;
                fb[nb] = *(const half8v*)&Bs[cur][br * 64 + (((ks * 2 + hq) ^ (br & 7)) << 3)];
            }
            #pragma unroll
            for (int mb = 0; mb < 2; ++mb) {
                int ar = wm * 64 + mb * 32 + l31;
                half8v fa = *(const half8v*)&Ah[cur][ar * 64 + (((ks * 2 + hq) ^ (ar & 7)) << 3)];
                acc[mb][0] = MFMAH(fa, fb[0], acc[mb][0]);
                acc[mb][1] = MFMAH(fa, fb[1], acc[mb][1]);
            }
        }
        __builtin_amdgcn_s_setprio(0);
        SBAR();
        if (kc + 2 < 16) QKV_STAGE(cur, kc + 2);
        cur ^= 1;
    }

    // epilogue: bias (+ Q scale) + bf16 scatter to (BH,L,DH)
    #pragma unroll
    for (int nb = 0; nb < 2; ++nb) {
        int n  = n0 + wn * 64 + nb * 32 + l31;   // fused n
        int nn = n & 1023;
        int h  = nn >> 6, dh = nn & 63;
        float bb = bias[nn];
        #pragma unroll
        for (int mb = 0; mb < 2; ++mb) {
            #pragma unroll
            for (int r = 0; r < 16; ++r) {
                int m  = m0 + wm * 64 + mb * 32 + (r & 3) + 8 * (r >> 2) + 4 * hq;
                int b  = m >> 11, i = m & (L_ - 1);
                out[((size_t)(b * H_ + h) * L_ + i) * DH_ + dh] = f2bf((acc[mb][nb][r] + bb) * osc);
            }
        }
    }
#undef QKV_STAGE
}

// ---------------------------------------------------------------------------
// Kernel 2: column sums D_j = sum_i x_i*exp2(S'_ij). Wave owns 64 j
// (kf[2][4] in regs -> each Q-fragment read feeds 2 MFMA).
// ---------------------------------------------------------------------------
__global__ __launch_bounds__(256) void col_stats_mfma(
    const unsigned short* __restrict__ Qb, const unsigned short* __restrict__ Kb,
    const float* __restrict__ x, float* __restrict__ Do)
{
    __shared__ unsigned short Qlds[2][128 * 64];
    __shared__ float xlds[L_];

    const int t    = threadIdx.x;
    const int lane = t & 63;
    const int wv   = t >> 6;
    const int l31  = lane & 31;
    const int hq   = lane >> 5;
    const int bh   = blockIdx.y;
    const int b    = bh >> 4;
    const int j0   = blockIdx.x * 256 + wv * 64;

    const int srow0 = (lane >> 3);
    const int ssl   = lane & 7;

    #pragma unroll
    for (int u = 0; u < 2; ++u) {
        int f = t + 256 * u;
        *(float4*)&xlds[f * 4] = *(const float4*)&x[(size_t)b * L_ + f * 4];
    }

    short8v kf[2][4];
    #pragma unroll
    for (int s = 0; s < 2; ++s) {
        const unsigned short* kp = Kb + ((size_t)bh * L_ + j0 + s * 32 + l31) * DH_ + hq * 8;
        #pragma unroll
        for (int c = 0; c < 4; ++c) kf[s][c] = *(const short8v*)(kp + c * 16);
    }

    float d0[16], d1[16];
    #pragma unroll
    for (int r = 0; r < 16; ++r) { d0[r] = 0.f; d1[r] = 0.f; }

#define CS_STAGE(bb, ich)                                                           \
    {                                                                               \
        _Pragma("unroll")                                                           \
        for (int u = 0; u < 4; ++u) {                                               \
            int ch  = wv * 4 + u;                                                   \
            int row = ch * 8 + srow0;                                               \
            gl_lds16(&Qb[((size_t)bh * L_ + (ich) * 128 + row) * DH_ + ((ssl ^ (row & 7)) << 3)], \
                     &Qlds[bb][ch * 512]);                                          \
        }                                                                           \
    }

    CS_STAGE(0, 0);
    CS_STAGE(1, 1);
    __syncthreads();
    int cur = 0;

    const int NT = L_ / 128;         // 16
    for (int ich = 0; ich < NT; ++ich) {
        if (ich < NT - 1) WAITV(4); else WAITV(0);
        SBAR();
        #pragma unroll
        for (int cc = 0; cc < 4; ++cc) {
            f32x16 a0 = {}, a1 = {};
            __builtin_amdgcn_s_setprio(1);
            #pragma unroll
            for (int c = 0; c < 4; ++c) {
                int qr = cc * 32 + l31;
                short8v qv = *(const short8v*)&Qlds[cur][qr * 64 + (((c * 2 + hq) ^ (qr & 7)) << 3)];
                a0 = MFMA32(kf[0][c], qv, a0);
                a1 = MFMA32(kf[1][c], qv, a1);
            }
            __builtin_amdgcn_s_setprio(0);
            float xi = xlds[ich * 128 + cc * 32 + l31];
            #pragma unroll
            for (int r = 0; r < 16; ++r) {
                d0[r] += xi * __builtin_amdgcn_exp2f(a0[r]);
                d1[r] += xi * __builtin_amdgcn_exp2f(a1[r]);
            }
        }
        SBAR();
        if (ich + 2 < NT) CS_STAGE(cur, ich + 2);
        cur ^= 1;
    }

    #pragma unroll
    for (int r = 0; r < 16; ++r) {
        #pragma unroll
        for (int off = 16; off > 0; off >>= 1) {
            d0[r] += __shfl_xor(d0[r], off);
            d1[r] += __shfl_xor(d1[r], off);
        }
    }
    if (l31 == 0) {
        #pragma unroll
        for (int r = 0; r < 16; ++r) {
            int jr = 4 * hq + (r & 3) + 8 * (r >> 2);
            Do[(size_t)bh * L_ + j0 + jr]      = d0[r];
            Do[(size_t)bh * L_ + j0 + 32 + jr] = d1[r];
        }
    }
#undef CS_STAGE
}

// ---------------------------------------------------------------------------
// Kernel 3: Vt[bh][dh][j] = bf16( x_j * V[bh][j][dh] / D_j )
// ---------------------------------------------------------------------------
__global__ __launch_bounds__(256) void vt_prep(
    const unsigned short* __restrict__ Vb, const float* __restrict__ x,
    const float* __restrict__ Do, unsigned short* __restrict__ Vt)
{
    const int bh = blockIdx.y;
    const int b  = bh >> 4;
    const int j  = blockIdx.x * 256 + threadIdx.x;
    const float s = x[(size_t)b * L_ + j] / Do[(size_t)bh * L_ + j];
    const unsigned short* vp = Vb + ((size_t)bh * L_ + j) * DH_;
    #pragma unroll
    for (int c = 0; c < 16; ++c) {
        ushort4 v = *(const ushort4*)&vp[c * 4];
        Vt[((size_t)bh * DH_ + c * 4 + 0) * L_ + j] = f2bf(bf2f(v.x) * s);
        Vt[((size_t)bh * DH_ + c * 4 + 1) * L_ + j] = f2bf(bf2f(v.y) * s);
        Vt[((size_t)bh * DH_ + c * 4 + 2) * L_ + j] = f2bf(bf2f(v.z) * s);
        Vt[((size_t)bh * DH_ + c * 4 + 3) * L_ + j] = f2bf(bf2f(v.w) * s);
    }
}

// ---------------------------------------------------------------------------
// Kernel 4: attention output. P = exp2(S'), O = x_i * (P @ Vt^T).
// 8 waves: (iwv = wv&3) 64-i groups x (jh = wv>>2) j-halves. Each j-half
// group stages its own K/V (counted-vmcnt, 2-deep); partial accO combined
// via padded LDS at the end. 2048 waves -> 2 waves/SIMD (was 1).
// ---------------------------------------------------------------------------
__global__ __launch_bounds__(512) void attn_out_mfma(
    const unsigned short* __restrict__ Qb, const unsigned short* __restrict__ Kb,
    const unsigned short* __restrict__ Vt, const float* __restrict__ x,
    _Float16* __restrict__ Of)
{
    __shared__ unsigned short Klds[2][2][64 * 64];   // [jh][buf]
    __shared__ unsigned short Vlds[2][2][64 * 64];
    __shared__ float comb[4][64 * 67];               // [iwv][lane*67 + k]

    const int t    = threadIdx.x;
    const int lane = t & 63;
    const int wv   = t >> 6;
    const int iwv  = wv & 3;          // i-group (64 rows)
    const int jh   = wv >> 2;         // j-half (0 or 1)
    const int l31  = lane & 31;
    const int hq   = lane >> 5;
    const int bh   = blockIdx.y;
    const int b    = bh >> 4, hh = bh & 15;
    const int iw   = blockIdx.x * 256 + iwv * 64;

    const int srow0 = (lane >> 3);
    const int ssl   = lane & 7;

    short8v qf[2][4];
    #pragma unroll
    for (int ig = 0; ig < 2; ++ig) {
        const unsigned short* qp = Qb + ((size_t)bh * L_ + iw + ig * 32 + l31) * DH_ + hq * 8;
        #pragma unroll
        for (int c = 0; c < 4; ++c) qf[ig][c] = *(const short8v*)(qp + c * 16);
    }

    f32x16 accO[2][2] = {};   // [igroup][dh-half]

#define AO_STAGE(bb, jt)                                                            \
    {                                                                               \
        _Pragma("unroll")                                                           \
        for (int u = 0; u < 2; ++u) {                                               \
            int ch  = iwv * 2 + u;                                                  \
            int row = ch * 8 + srow0;                                               \
            gl_lds16(&Kb[((size_t)bh * L_ + (jt) * 64 + row) * DH_ + ((ssl ^ (row & 7)) << 3)], \
                     &Klds[jh][bb][ch * 512]);                                      \
            gl_lds16(&Vt[((size_t)bh * DH_ + row) * L_ + (jt) * 64 + ((ssl ^ (row & 7)) << 3)], \
                     &Vlds[jh][bb][ch * 512]);                                      \
        }                                                                           \
    }

    AO_STAGE(0, jh * 16 + 0);
    AO_STAGE(1, jh * 16 + 1);
    __syncthreads();
    int cur = 0;

    for (int ltj = 0; ltj < 16; ++ltj) {
        if (ltj < 15) WAITV(4); else WAITV(0);
        SBAR();

        // ---- QK^T (two i-groups share each K-fragment) + T12 P packing ----
        uint4 pa[2][4];
        #pragma unroll
        for (int js = 0; js < 2; ++js) {
            f32x16 as0 = {}, as1 = {};
            __builtin_amdgcn_s_setprio(1);
            #pragma unroll
            for (int c = 0; c < 4; ++c) {
                int krow = js * 32 + l31;
                short8v kfr = *(const short8v*)&Klds[jh][cur][krow * 64 + (((c * 2 + hq) ^ (krow & 7)) << 3)];
                as0 = MFMA32(kfr, qf[0][c], as0);
                as1 = MFMA32(kfr, qf[1][c], as1);
            }
            __builtin_amdgcn_s_setprio(0);
            #pragma unroll
            for (int ig = 0; ig < 2; ++ig) {
                const f32x16& as = (ig == 0) ? as0 : as1;
                float p[16];
                #pragma unroll
                for (int r = 0; r < 16; ++r) p[r] = __builtin_amdgcn_exp2f(as[r]);

                unsigned P0 = pack2_bf16(p[0], p[1]);
                unsigned P1 = pack2_bf16(p[2], p[3]);
                unsigned Q0 = pack2_bf16(p[4], p[5]);
                unsigned Q1 = pack2_bf16(p[6], p[7]);
                asm("v_permlane32_swap_b32 %0, %1" : "+v"(P0), "+v"(Q0));
                asm("v_permlane32_swap_b32 %0, %1" : "+v"(P1), "+v"(Q1));
                pa[ig][js * 2 + 0] = make_uint4(P0, P1, Q0, Q1);

                unsigned R0 = pack2_bf16(p[8],  p[9]);
                unsigned R1 = pack2_bf16(p[10], p[11]);
                unsigned S0 = pack2_bf16(p[12], p[13]);
                unsigned S1 = pack2_bf16(p[14], p[15]);
                asm("v_permlane32_swap_b32 %0, %1" : "+v"(R0), "+v"(S0));
                asm("v_permlane32_swap_b32 %0, %1" : "+v"(R1), "+v"(S1));
                pa[ig][js * 2 + 1] = make_uint4(R0, R1, S0, S1);
            }
        }

        // ---- O += P · Vt^T (two i-groups share each V-fragment) ----
        __builtin_amdgcn_s_setprio(1);
        #pragma unroll
        for (int c = 0; c < 4; ++c) {
            union { uint4 u; short8v s; } pa0, pa1;
            pa0.u = pa[0][c]; pa1.u = pa[1][c];
            int r0 = l31, r1 = 32 + l31;
            short8v vf0 = *(const short8v*)&Vlds[jh][cur][r0 * 64 + (((c * 2 + hq) ^ (r0 & 7)) << 3)];
            short8v vf1 = *(const short8v*)&Vlds[jh][cur][r1 * 64 + (((c * 2 + hq) ^ (r1 & 7)) << 3)];
            accO[0][0] = MFMA32(pa0.s, vf0, accO[0][0]);
            accO[0][1] = MFMA32(pa0.s, vf1, accO[0][1]);
            accO[1][0] = MFMA32(pa1.s, vf0, accO[1][0]);
            accO[1][1] = MFMA32(pa1.s, vf1, accO[1][1]);
        }
        __builtin_amdgcn_s_setprio(0);
        SBAR();
        if (ltj + 2 < 16) AO_STAGE(cur, jh * 16 + ltj + 2);
        cur ^= 1;
    }

    // ---- combine j-halves via LDS (stride-67 pad: conflict-free) ----
    if (jh == 1) {
        float* cb = &comb[iwv][lane * 67];
        #pragma unroll
        for (int g = 0; g < 2; ++g)
            #pragma unroll
            for (int h = 0; h < 2; ++h)
                #pragma unroll
                for (int r = 0; r < 16; ++r)
                    cb[(g * 2 + h) * 16 + r] = accO[g][h][r];
    }
    __syncthreads();
    if (jh == 0) {
        const float* cb = &comb[iwv][lane * 67];
        #pragma unroll
        for (int g = 0; g < 2; ++g)
            #pragma unroll
            for (int h = 0; h < 2; ++h)
                #pragma unroll
                for (int r = 0; r < 16; ++r)
                    accO[g][h][r] += cb[(g * 2 + h) * 16 + r];

        #pragma unroll
        for (int ig = 0; ig < 2; ++ig) {
            #pragma unroll
            for (int q = 0; q < 4; ++q) {
                float4 xq = *(const float4*)&x[(size_t)b * L_ + iw + ig * 32 + 4 * hq + 8 * q];
                const float xs[4] = { xq.x, xq.y, xq.z, xq.w };
                #pragma unroll
                for (int k = 0; k < 4; ++k) {
                    int r    = q * 4 + k;
                    int irow = iw + ig * 32 + 4 * hq + 8 * q + k;
                    size_t base = ((size_t)b * L_ + irow) * E_ + hh * DH_;
                    Of[base + l31]      = (_Float16)(accO[ig][0][r] * xs[k]);
                    Of[base + 32 + l31] = (_Float16)(accO[ig][1][r] * xs[k]);
                }
            }
        }
    }
#undef AO_STAGE
}

// ---------------------------------------------------------------------------
// Kernel 5a: y_init — y[i] = b2[0].
// ---------------------------------------------------------------------------
__global__ __launch_bounds__(256) void y_init(float* __restrict__ y, const float* __restrict__ b2)
{
    y[blockIdx.x * 256 + threadIdx.x] = b2[0];
}

// ---------------------------------------------------------------------------
// Kernel 5b: fused MLP, fp16 MFMA, 128x128, BK=64, counted-vmcnt pipeline.
// (R11-proven version: 63.5 us)
// ---------------------------------------------------------------------------
__global__ __launch_bounds__(256) void mlp_mfma(
    const _Float16* __restrict__ Of, const _Float16* __restrict__ W1t,
    const float* __restrict__ b1, const float* __restrict__ W2,
    float* __restrict__ y)
{
    __shared__ _Float16 Oh[2][128 * 64];
    __shared__ _Float16 Wh[2][128 * 64];

    const int t    = threadIdx.x;
    const int lane = t & 63;
    const int w    = t >> 6;
    const int l31  = lane & 31;
    const int hq   = lane >> 5;
    const int wm   = w >> 1, wn = w & 1;
    const int m0   = blockIdx.x * 128;
    const int n0   = blockIdx.y * 128;

    const int srow0 = (lane >> 3);
    const int ssl   = lane & 7;

    f32x16 acc[2][2] = {};

#define MLP_STAGE(bb, kc)                                                          \
    {                                                                              \
        _Pragma("unroll")                                                          \
        for (int u = 0; u < 4; ++u) {                                              \
            int ch  = w * 4 + u;                                                   \
            int row = ch * 8 + srow0;                                              \
            gl_lds16(&Of[(size_t)(m0 + row) * E_ + (kc) * 64 + ((ssl ^ (row & 7)) << 3)], \
                     &Oh[bb][ch * 512]);                                           \
            gl_lds16(&W1t[(size_t)(n0 + row) * E_ + (kc) * 64 + ((ssl ^ (row & 7)) << 3)], \
                     &Wh[bb][ch * 512]);                                           \
        }                                                                          \
    }

    MLP_STAGE(0, 0);
    MLP_STAGE(1, 1);
    __syncthreads();
    int cur = 0;

    for (int kc = 0; kc < 16; ++kc) {
        if (kc < 15) WAITV(8); else WAITV(0);
        SBAR();
        __builtin_amdgcn_s_setprio(1);
        #pragma unroll
        for (int ks = 0; ks < 4; ++ks) {
            half8v fb[2];
            #pragma unroll
            for (int nb = 0; nb < 2; ++nb) {
                int br = wn * 64 + nb * 32 + l31;
                fb[nb] = *(const half8v*)&Wh[cur][br * 64 + (((ks * 2 + hq) ^ (br & 7)) << 3)];
            }
            #pragma unroll
            for (int mb = 0; mb < 2; ++mb) {
                int ar = wm * 64 + mb * 32 + l31;
                half8v fa = *(const half8v*)&Oh[cur][ar * 64 + (((ks * 2 + hq) ^ (ar & 7)) << 3)];
                acc[mb][0] = MFMAH(fa, fb[0], acc[mb][0]);
                acc[mb][1] = MFMAH(fa, fb[1], acc[mb][1]);
            }
        }
        __builtin_amdgcn_s_setprio(0);
        SBAR();
        if (kc + 2 < 16) MLP_STAGE(cur, kc + 2);
        cur ^= 1;
    }

    // epilogue: gelu + W2 dot; reduce over 32 lanes; atomicAdd per row.
    const int hid0 = n0 + wn * 64 + l31;
    const float bb0 = b1[hid0],      w20 = W2[hid0];
    const float bb1 = b1[hid0 + 32], w21 = W2[hid0 + 32];
    #pragma unroll
    for (int mb = 0; mb < 2; ++mb) {
        #pragma unroll
        for (int r = 0; r < 16; ++r) {
            float h0 = acc[mb][0][r] + bb0;
            float h1 = acc[mb][1][r] + bb1;
            float s  = 0.5f * h0 * (1.0f + erf_fast(h0 * 0.70710678f)) * w20
                     + 0.5f * h1 * (1.0f + erf_fast(h1 * 0.70710678f)) * w21;
            #pragma unroll
            for (int off = 16; off > 0; off >>= 1) s += __shfl_xor(s, off);
            if (l31 == 0) {
                int m = m0 + wm * 64 + mb * 32 + (r & 3) + 8 * (r >> 2) + 4 * hq;
                atomicAdd(&y[m], s);
            }
        }
    }
#undef MLP_STAGE
}

// ---------------------------------------------------------------------------
extern "C" void kernel_launch(void* const* d_in, const int* in_sizes, int n_in,
                              void* d_out, int out_size, void* d_ws, size_t ws_size,
                              hipStream_t stream)
{
    const float* x  = (const float*)d_in[0];
    const float* z  = (const float*)d_in[1];
    const float* Wq = (const float*)d_in[2];
    const float* bq = (const float*)d_in[3];
    const float* Wk = (const float*)d_in[4];
    const float* bk = (const float*)d_in[5];
    const float* Wv = (const float*)d_in[6];
    const float* bv = (const float*)d_in[7];
    const float* W1 = (const float*)d_in[8];
    const float* b1 = (const float*)d_in[9];
    const float* W2 = (const float*)d_in[10];
    const float* b2 = (const float*)d_in[11];
    float* y = (float*)d_out;

    const size_t NQ = (size_t)BH_ * L_ * DH_;        // 4.19M elems
    unsigned short* p = (unsigned short*)d_ws;
    unsigned short* Qb  = p;  p += NQ;               // Qb|Kb|Vb contiguous
    unsigned short* Kb  = p;  p += NQ;
    unsigned short* Vb  = p;  p += NQ;
    unsigned short* Vt  = p;  p += NQ;
    _Float16* zh  = (_Float16*)p;  p += (size_t)NROW_ * E_;
    _Float16* Tq  = (_Float16*)p;  p += (size_t)E_ * E_;   // Tq|Tk|Tv contiguous
    _Float16* Tk  = (_Float16*)p;  p += (size_t)E_ * E_;
    _Float16* Tv  = (_Float16*)p;  p += (size_t)E_ * E_;
    _Float16* W1t = (_Float16*)p;  p += (size_t)HID_ * E_;
    _Float16* Ofp = (_Float16*)p;  p += (size_t)NROW_ * E_;
    float* Dw = (float*)p;

    zh_prep<<<dim3((NROW_ * E_) / (256 * 8)), 256, 0, stream>>>(z, zh);
    wprep3 <<<dim3(E_ / 64, E_ / 64, 3), 256, 0, stream>>>(Wq, Wk, Wv, Tq, Tk, Tv);
    w1prep <<<dim3(HID_ / 64, E_ / 64), 256, 0, stream>>>(W1, W1t);

    qkv_mfma<<<dim3(NROW_ / 128, 3 * E_ / 128), 256, 0, stream>>>(
        zh, Tq, bq, bk, bv, Qb);

    col_stats_mfma<<<dim3(L_ / 256, BH_), 256, 0, stream>>>(Qb, Kb, x, Dw);

    vt_prep<<<dim3(L_ / 256, BH_), 256, 0, stream>>>(Vb, x, Dw, Vt);

    attn_out_mfma<<<dim3(L_ / 256, BH_), 512, 0, stream>>>(Qb, Kb, Vt, x, Ofp);

    y_init<<<dim3(NROW_ / 256), 256, 0, stream>>>(y, b2);

    mlp_mfma<<<dim3(NROW_ / 128, HID_ / 128), 256, 0, stream>>>(
        Ofp, W1t, b1, W2, y);
}

// Round 15
// 204.796 us; speedup vs baseline: 1.0832x; 1.0113x over previous
//
#include <hip/hip_runtime.h>
#include <hip/hip_bf16.h>
#include <math.h>

#define B_    2
#define L_    2048
#define E_    1024
#define H_    16
#define DH_   64
#define HID_  4096
#define NROW_ (B_*L_)   // 4096
#define BH_   (B_*H_)   // 32

// 0.125 (1/sqrt(DH)) * log2(e): Q pre-scale so P = exp2(S')
#define QSCL  0.18033688011112042f

typedef __attribute__((ext_vector_type(8)))  short    short8v;
typedef _Float16 half8v __attribute__((ext_vector_type(8)));
typedef __attribute__((ext_vector_type(16))) float    f32x16;

#define MFMA32(A, Bv, C) __builtin_amdgcn_mfma_f32_32x32x16_bf16((A), (Bv), (C), 0, 0, 0)
#define MFMAH(A, Bv, C)  __builtin_amdgcn_mfma_f32_32x32x16_f16((A), (Bv), (C), 0, 0, 0)

#define WAITV(N) asm volatile("s_waitcnt vmcnt(" #N ")" ::: "memory")
#define SBAR()   __builtin_amdgcn_s_barrier()

// float->bf16 round-half-up (2 ops).
__device__ __forceinline__ unsigned short f2bf(float f) {
    union { float f; unsigned u; } v; v.f = f;
    return (unsigned short)((v.u + 0x8000u) >> 16);
}
// pack two floats -> {bf16(hi), bf16(lo)} in 3 VALU ops via v_perm_b32
__device__ __forceinline__ unsigned pack2_bf16(float lo, float hi) {
    union { float f; unsigned u; } a, b; a.f = lo; b.f = hi;
    return __builtin_amdgcn_perm(b.u + 0x8000u, a.u + 0x8000u, 0x07060302u);
}
__device__ __forceinline__ float bf2f(unsigned short u) {
    union { unsigned u; float f; } v; v.u = ((unsigned)u) << 16;
    return v.f;
}

// async global->LDS, 16B per lane. Dest is wave-uniform base + lane*16.
__device__ __forceinline__ void gl_lds16(const void* g, void* l) {
    __builtin_amdgcn_global_load_lds(
        (const __attribute__((address_space(1))) unsigned int*)g,
        (__attribute__((address_space(3))) unsigned int*)l, 16, 0, 0);
}

// Abramowitz-Stegun 7.1.26, |abs err| < 1.5e-7
__device__ __forceinline__ float erf_fast(float v) {
    float a = fabsf(v);
    float t = __builtin_amdgcn_rcpf(1.0f + 0.3275911f * a);
    float p = t * (0.254829592f + t * (-0.284496736f + t * (1.421413741f +
              t * (-1.453152027f + t * 1.061405429f))));
    float r = 1.0f - p * __expf(-a * a);
    return copysignf(r, v);
}

// ---------------------------------------------------------------------------
// Prep A: cast z (fp32) -> zh (fp16), same layout.
// ---------------------------------------------------------------------------
__global__ __launch_bounds__(256) void zh_prep(
    const float* __restrict__ z, _Float16* __restrict__ zh)
{
    const size_t i = ((size_t)blockIdx.x * 256 + threadIdx.x) * 8;
    float4 a = *(const float4*)&z[i];
    float4 b = *(const float4*)&z[i + 4];
    union { _Float16 h[8]; half8v v; } o;
    o.h[0] = (_Float16)a.x; o.h[1] = (_Float16)a.y;
    o.h[2] = (_Float16)a.z; o.h[3] = (_Float16)a.w;
    o.h[4] = (_Float16)b.x; o.h[5] = (_Float16)b.y;
    o.h[6] = (_Float16)b.z; o.h[7] = (_Float16)b.w;
    *(half8v*)&zh[i] = o.v;
}

// ---------------------------------------------------------------------------
// Prep B: transpose+cast Wq/Wk/Wv (ExE fp32) -> T* (n-major fp16, contiguous).
// ---------------------------------------------------------------------------
__global__ __launch_bounds__(256) void wprep3(
    const float* __restrict__ Wq, const float* __restrict__ Wk,
    const float* __restrict__ Wv,
    _Float16* __restrict__ Tq, _Float16* __restrict__ Tk,
    _Float16* __restrict__ Tv)
{
    const float* src = (blockIdx.z == 0) ? Wq : (blockIdx.z == 1) ? Wk : Wv;
    _Float16*    dst = (blockIdx.z == 0) ? Tq : (blockIdx.z == 1) ? Tk : Tv;
    __shared__ float tile[64][65];
    const int t  = threadIdx.x;
    const int r0 = blockIdx.y * 64, c0 = blockIdx.x * 64;
    #pragma unroll
    for (int u = 0; u < 4; ++u) {
        int f = t + 256 * u, row = f >> 4, c4 = (f & 15) << 2;
        *(float4*)&tile[row][c4] = *(const float4*)&src[(size_t)(r0 + row) * E_ + c0 + c4];
    }
    __syncthreads();
    #pragma unroll
    for (int u = 0; u < 4; ++u) {
        int f = t + 256 * u, c = f >> 4, r4 = (f & 15) << 2;
        union { _Float16 h[4]; uint2 u2; } pk;
        pk.h[0] = (_Float16)tile[r4 + 0][c];
        pk.h[1] = (_Float16)tile[r4 + 1][c];
        pk.h[2] = (_Float16)tile[r4 + 2][c];
        pk.h[3] = (_Float16)tile[r4 + 3][c];
        *(uint2*)&dst[(size_t)(c0 + c) * E_ + r0 + r4] = pk.u2;
    }
}

// ---------------------------------------------------------------------------
// Prep C: transpose+cast W1 (E x HID fp32) -> W1t (HID x E fp16).
// ---------------------------------------------------------------------------
__global__ __launch_bounds__(256) void w1prep(
    const float* __restrict__ W1, _Float16* __restrict__ W1t)
{
    __shared__ float tile[64][65];
    const int t  = threadIdx.x;
    const int r0 = blockIdx.y * 64, c0 = blockIdx.x * 64;
    #pragma unroll
    for (int u = 0; u < 4; ++u) {
        int f = t + 256 * u, row = f >> 4, c4 = (f & 15) << 2;
        *(float4*)&tile[row][c4] = *(const float4*)&W1[(size_t)(r0 + row) * HID_ + c0 + c4];
    }
    __syncthreads();
    #pragma unroll
    for (int u = 0; u < 4; ++u) {
        int f = t + 256 * u, c = f >> 4, r4 = (f & 15) << 2;
        union { _Float16 h[4]; uint2 u2; } pk;
        pk.h[0] = (_Float16)tile[r4 + 0][c];
        pk.h[1] = (_Float16)tile[r4 + 1][c];
        pk.h[2] = (_Float16)tile[r4 + 2][c];
        pk.h[3] = (_Float16)tile[r4 + 3][c];
        *(uint2*)&W1t[(size_t)(c0 + c) * E_ + r0 + r4] = pk.u2;
    }
}

// ---------------------------------------------------------------------------
// Kernel 1: fused QKV projection (single dispatch over n=3072), fp16 MFMA,
// 128x128 tile, BK=64, 4 waves, counted-vmcnt 2-deep pipeline.
// ---------------------------------------------------------------------------
__global__ __launch_bounds__(256) void qkv_mfma(
    const _Float16* __restrict__ zh,
    const _Float16* __restrict__ Tall,      // fused [3072][1024]
    const float* __restrict__ bq, const float* __restrict__ bk,
    const float* __restrict__ bv,
    unsigned short* __restrict__ outQKV)    // Qb | Kb | Vb contiguous
{
    const int which = blockIdx.y >> 3;      // 1024/128 = 8 tiles per weight
    const float* bias = (which == 0) ? bq : (which == 1) ? bk : bv;
    const float  osc  = (which == 0) ? QSCL : 1.0f;
    unsigned short* out = outQKV + (size_t)which * ((size_t)BH_ * L_ * DH_);

    __shared__ _Float16 Ah[2][128 * 64];
    __shared__ _Float16 Bs[2][128 * 64];

    const int t    = threadIdx.x;
    const int lane = t & 63;
    const int w    = t >> 6;
    const int l31  = lane & 31;
    const int hq   = lane >> 5;
    const int wm   = w >> 1, wn = w & 1;
    const int m0   = blockIdx.x * 128;
    const int n0   = blockIdx.y * 128;      // global fused n

    const int srow0 = (lane >> 3);
    const int ssl   = lane & 7;

    f32x16 acc[2][2] = {};

#define QKV_STAGE(bb, kc)                                                          \
    {                                                                              \
        _Pragma("unroll")                                                          \
        for (int u = 0; u < 4; ++u) {                                              \
            int ch  = w * 4 + u;                                                   \
            int row = ch * 8 + srow0;                                              \
            gl_lds16(&zh[(size_t)(m0 + row) * E_ + (kc) * 64 + ((ssl ^ (row & 7)) << 3)], \
                     &Ah[bb][ch * 512]);                                           \
            gl_lds16(&Tall[(size_t)(n0 + row) * E_ + (kc) * 64 + ((ssl ^ (row & 7)) << 3)], \
                     &Bs[bb][ch * 512]);                                           \
        }                                                                          \
    }

    QKV_STAGE(0, 0);
    QKV_STAGE(1, 1);
    __syncthreads();
    int cur = 0;

    for (int kc = 0; kc < 16; ++kc) {
        if (kc < 15) WAITV(8); else WAITV(0);
        SBAR();
        __builtin_amdgcn_s_setprio(1);
        #pragma unroll
        for (int ks = 0; ks < 4; ++ks) {
            half8v fb[2];
            #pragma unroll
            for (int nb = 0; nb < 2; ++nb) {
                int br = wn * 64 + nb * 32 + l31;
                fb[nb] = *(const half8v*)&Bs[cur][br * 64 + (((ks * 2 + hq) ^ (br & 7)) << 3)];
            }
            #pragma unroll
            for (int mb = 0; mb < 2; ++mb) {
                int ar = wm * 64 + mb * 32 + l31;
                half8v fa = *(const half8v*)&Ah[cur][ar * 64 + (((ks * 2 + hq) ^ (ar & 7)) << 3)];
                acc[mb][0] = MFMAH(fa, fb[0], acc[mb][0]);
                acc[mb][1] = MFMAH(fa, fb[1], acc[mb][1]);
            }
        }
        __builtin_amdgcn_s_setprio(0);
        SBAR();
        if (kc + 2 < 16) QKV_STAGE(cur, kc + 2);
        cur ^= 1;
    }

    // epilogue: bias (+ Q scale) + bf16 scatter to (BH,L,DH)
    #pragma unroll
    for (int nb = 0; nb < 2; ++nb) {
        int n  = n0 + wn * 64 + nb * 32 + l31;   // fused n
        int nn = n & 1023;
        int h  = nn >> 6, dh = nn & 63;
        float bb = bias[nn];
        #pragma unroll
        for (int mb = 0; mb < 2; ++mb) {
            #pragma unroll
            for (int r = 0; r < 16; ++r) {
                int m  = m0 + wm * 64 + mb * 32 + (r & 3) + 8 * (r >> 2) + 4 * hq;
                int b  = m >> 11, i = m & (L_ - 1);
                out[((size_t)(b * H_ + h) * L_ + i) * DH_ + dh] = f2bf((acc[mb][nb][r] + bb) * osc);
            }
        }
    }
#undef QKV_STAGE
}

// ---------------------------------------------------------------------------
// Kernel 2: column sums D_j = sum_i x_i*exp2(S'_ij). 8 waves: 4 j-groups
// (64 j each, kf[2][4] in regs) x 2 i-halves. Each i-half group stages its
// own Q; partial sums combined via LDS. 2 waves/SIMD (was 1).
// ---------------------------------------------------------------------------
__global__ __launch_bounds__(512) void col_stats_mfma(
    const unsigned short* __restrict__ Qb, const unsigned short* __restrict__ Kb,
    const float* __restrict__ x, float* __restrict__ Do)
{
    __shared__ unsigned short Qlds[2][2][128 * 64];   // [ih][buf]
    __shared__ float xlds[L_];
    __shared__ float cD[4][64];                       // [jwv][j in wave]

    const int t    = threadIdx.x;
    const int lane = t & 63;
    const int wv   = t >> 6;
    const int jwv  = wv & 3;          // j-group
    const int ih   = wv >> 2;         // i-half
    const int l31  = lane & 31;
    const int hq   = lane >> 5;
    const int bh   = blockIdx.y;
    const int b    = bh >> 4;
    const int j0   = blockIdx.x * 256 + jwv * 64;

    const int srow0 = (lane >> 3);
    const int ssl   = lane & 7;

    {   // stage full x row (8KB), 512 threads x 4 floats
        *(float4*)&xlds[t * 4] = *(const float4*)&x[(size_t)b * L_ + t * 4];
    }

    short8v kf[2][4];
    #pragma unroll
    for (int s = 0; s < 2; ++s) {
        const unsigned short* kp = Kb + ((size_t)bh * L_ + j0 + s * 32 + l31) * DH_ + hq * 8;
        #pragma unroll
        for (int c = 0; c < 4; ++c) kf[s][c] = *(const short8v*)(kp + c * 16);
    }

    float d0[16], d1[16];
    #pragma unroll
    for (int r = 0; r < 16; ++r) { d0[r] = 0.f; d1[r] = 0.f; }

    // i-chunks for this half: global chunk = ih*8 + lt, lt in [0,8)
#define CS_STAGE(bb, lt)                                                            \
    {                                                                               \
        _Pragma("unroll")                                                           \
        for (int u = 0; u < 4; ++u) {                                               \
            int ch  = jwv * 4 + u;                                                  \
            int row = ch * 8 + srow0;                                               \
            gl_lds16(&Qb[((size_t)bh * L_ + (size_t)(ih * 8 + (lt)) * 128 + row) * DH_ + ((ssl ^ (row & 7)) << 3)], \
                     &Qlds[ih][bb][ch * 512]);                                      \
        }                                                                           \
    }

    CS_STAGE(0, 0);
    CS_STAGE(1, 1);
    __syncthreads();                 // drains loads AND xlds ds_writes
    int cur = 0;

    for (int lt = 0; lt < 8; ++lt) {
        if (lt < 7) WAITV(4); else WAITV(0);
        SBAR();
        #pragma unroll
        for (int cc = 0; cc < 4; ++cc) {
            f32x16 a0 = {}, a1 = {};
            __builtin_amdgcn_s_setprio(1);
            #pragma unroll
            for (int c = 0; c < 4; ++c) {
                int qr = cc * 32 + l31;
                short8v qv = *(const short8v*)&Qlds[ih][cur][qr * 64 + (((c * 2 + hq) ^ (qr & 7)) << 3)];
                a0 = MFMA32(kf[0][c], qv, a0);
                a1 = MFMA32(kf[1][c], qv, a1);
            }
            __builtin_amdgcn_s_setprio(0);
            float xi = xlds[(ih * 8 + lt) * 128 + cc * 32 + l31];
            #pragma unroll
            for (int r = 0; r < 16; ++r) {
                d0[r] += xi * __builtin_amdgcn_exp2f(a0[r]);
                d1[r] += xi * __builtin_amdgcn_exp2f(a1[r]);
            }
        }
        SBAR();
        if (lt + 2 < 8) CS_STAGE(cur, lt + 2);
        cur ^= 1;
    }

    #pragma unroll
    for (int r = 0; r < 16; ++r) {
        #pragma unroll
        for (int off = 16; off > 0; off >>= 1) {
            d0[r] += __shfl_xor(d0[r], off);
            d1[r] += __shfl_xor(d1[r], off);
        }
    }
    // combine the two i-halves via LDS
    if (ih == 1 && l31 == 0) {
        #pragma unroll
        for (int r = 0; r < 16; ++r) {
            int jr = 4 * hq + (r & 3) + 8 * (r >> 2);
            cD[jwv][jr]      = d0[r];
            cD[jwv][32 + jr] = d1[r];
        }
    }
    __syncthreads();
    if (ih == 0 && l31 == 0) {
        #pragma unroll
        for (int r = 0; r < 16; ++r) {
            int jr = 4 * hq + (r & 3) + 8 * (r >> 2);
            Do[(size_t)bh * L_ + j0 + jr]      = d0[r] + cD[jwv][jr];
            Do[(size_t)bh * L_ + j0 + 32 + jr] = d1[r] + cD[jwv][32 + jr];
        }
    }
#undef CS_STAGE
}

// ---------------------------------------------------------------------------
// Kernel 3: Vt[bh][dh][j] = bf16( x_j * V[bh][j][dh] / D_j ), coalesced via
// 64x64 LDS tile transpose (old version read V at 128B/lane stride).
// ---------------------------------------------------------------------------
__global__ __launch_bounds__(256) void vt_prep(
    const unsigned short* __restrict__ Vb, const float* __restrict__ x,
    const float* __restrict__ Do, unsigned short* __restrict__ Vt)
{
    __shared__ float sc[64];
    __shared__ unsigned short vt[64][66];   // [j][dh], padded

    const int t  = threadIdx.x;
    const int bh = blockIdx.y;
    const int b  = bh >> 4;
    const int j0 = blockIdx.x * 64;

    if (t < 64) {
        int j = j0 + t;
        sc[t] = x[(size_t)b * L_ + j] / Do[(size_t)bh * L_ + j];
    }
    __syncthreads();

    // stage+scale: coalesced reads (16B/lane), idx -> (j-row, 8-dh chunk)
    #pragma unroll
    for (int u = 0; u < 2; ++u) {
        int idx = t + 256 * u;
        int row = idx >> 3, off = (idx & 7) * 8;
        short8v v = *(const short8v*)&Vb[((size_t)bh * L_ + j0 + row) * DH_ + off];
        float s = sc[row];
        const unsigned short* vs = (const unsigned short*)&v;
        #pragma unroll
        for (int k = 0; k < 8; ++k)
            vt[row][off + k] = f2bf(bf2f(vs[k]) * s);
    }
    __syncthreads();

    // transposed write: coalesced 16B stores of 8 consecutive j per dh
    #pragma unroll
    for (int u = 0; u < 2; ++u) {
        int idx = t + 256 * u;
        int dh = idx >> 3, js = (idx & 7) * 8;
        unsigned short o[8];
        #pragma unroll
        for (int k = 0; k < 8; ++k) o[k] = vt[js + k][dh];
        *(short8v*)&Vt[((size_t)bh * DH_ + dh) * L_ + j0 + js] = *(const short8v*)o;
    }
}

// ---------------------------------------------------------------------------
// Kernel 4: attention output. P = exp2(S'), O = x_i * (P @ Vt^T).
// 8 waves: 4 i-groups (64 i) x 2 j-halves; counted-vmcnt 2-deep pipelines;
// T12 in-register P; partial accO combined via padded LDS. (R14-proven)
// ---------------------------------------------------------------------------
__global__ __launch_bounds__(512) void attn_out_mfma(
    const unsigned short* __restrict__ Qb, const unsigned short* __restrict__ Kb,
    const unsigned short* __restrict__ Vt, const float* __restrict__ x,
    _Float16* __restrict__ Of)
{
    __shared__ unsigned short Klds[2][2][64 * 64];   // [jh][buf]
    __shared__ unsigned short Vlds[2][2][64 * 64];
    __shared__ float comb[4][64 * 67];               // [iwv][lane*67 + k]

    const int t    = threadIdx.x;
    const int lane = t & 63;
    const int wv   = t >> 6;
    const int iwv  = wv & 3;          // i-group (64 rows)
    const int jh   = wv >> 2;         // j-half (0 or 1)
    const int l31  = lane & 31;
    const int hq   = lane >> 5;
    const int bh   = blockIdx.y;
    const int b    = bh >> 4, hh = bh & 15;
    const int iw   = blockIdx.x * 256 + iwv * 64;

    const int srow0 = (lane >> 3);
    const int ssl   = lane & 7;

    short8v qf[2][4];
    #pragma unroll
    for (int ig = 0; ig < 2; ++ig) {
        const unsigned short* qp = Qb + ((size_t)bh * L_ + iw + ig * 32 + l31) * DH_ + hq * 8;
        #pragma unroll
        for (int c = 0; c < 4; ++c) qf[ig][c] = *(const short8v*)(qp + c * 16);
    }

    f32x16 accO[2][2] = {};   // [igroup][dh-half]

#define AO_STAGE(bb, jt)                                                            \
    {                                                                               \
        _Pragma("unroll")                                                           \
        for (int u = 0; u < 2; ++u) {                                               \
            int ch  = iwv * 2 + u;                                                  \
            int row = ch * 8 + srow0;                                               \
            gl_lds16(&Kb[((size_t)bh * L_ + (jt) * 64 + row) * DH_ + ((ssl ^ (row & 7)) << 3)], \
                     &Klds[jh][bb][ch * 512]);                                      \
            gl_lds16(&Vt[((size_t)bh * DH_ + row) * L_ + (jt) * 64 + ((ssl ^ (row & 7)) << 3)], \
                     &Vlds[jh][bb][ch * 512]);                                      \
        }                                                                           \
    }

    AO_STAGE(0, jh * 16 + 0);
    AO_STAGE(1, jh * 16 + 1);
    __syncthreads();
    int cur = 0;

    for (int ltj = 0; ltj < 16; ++ltj) {
        if (ltj < 15) WAITV(4); else WAITV(0);
        SBAR();

        // ---- QK^T (two i-groups share each K-fragment) + T12 P packing ----
        uint4 pa[2][4];
        #pragma unroll
        for (int js = 0; js < 2; ++js) {
            f32x16 as0 = {}, as1 = {};
            __builtin_amdgcn_s_setprio(1);
            #pragma unroll
            for (int c = 0; c < 4; ++c) {
                int krow = js * 32 + l31;
                short8v kfr = *(const short8v*)&Klds[jh][cur][krow * 64 + (((c * 2 + hq) ^ (krow & 7)) << 3)];
                as0 = MFMA32(kfr, qf[0][c], as0);
                as1 = MFMA32(kfr, qf[1][c], as1);
            }
            __builtin_amdgcn_s_setprio(0);
            #pragma unroll
            for (int ig = 0; ig < 2; ++ig) {
                const f32x16& as = (ig == 0) ? as0 : as1;
                float p[16];
                #pragma unroll
                for (int r = 0; r < 16; ++r) p[r] = __builtin_amdgcn_exp2f(as[r]);

                unsigned P0 = pack2_bf16(p[0], p[1]);
                unsigned P1 = pack2_bf16(p[2], p[3]);
                unsigned Q0 = pack2_bf16(p[4], p[5]);
                unsigned Q1 = pack2_bf16(p[6], p[7]);
                asm("v_permlane32_swap_b32 %0, %1" : "+v"(P0), "+v"(Q0));
                asm("v_permlane32_swap_b32 %0, %1" : "+v"(P1), "+v"(Q1));
                pa[ig][js * 2 + 0] = make_uint4(P0, P1, Q0, Q1);

                unsigned R0 = pack2_bf16(p[8],  p[9]);
                unsigned R1 = pack2_bf16(p[10], p[11]);
                unsigned S0 = pack2_bf16(p[12], p[13]);
                unsigned S1 = pack2_bf16(p[14], p[15]);
                asm("v_permlane32_swap_b32 %0, %1" : "+v"(R0), "+v"(S0));
                asm("v_permlane32_swap_b32 %0, %1" : "+v"(R1), "+v"(S1));
                pa[ig][js * 2 + 1] = make_uint4(R0, R1, S0, S1);
            }
        }

        // ---- O += P · Vt^T (two i-groups share each V-fragment) ----
        __builtin_amdgcn_s_setprio(1);
        #pragma unroll
        for (int c = 0; c < 4; ++c) {
            union { uint4 u; short8v s; } pa0, pa1;
            pa0.u = pa[0][c]; pa1.u = pa[1][c];
            int r0 = l31, r1 = 32 + l31;
            short8v vf0 = *(const short8v*)&Vlds[jh][cur][r0 * 64 + (((c * 2 + hq) ^ (r0 & 7)) << 3)];
            short8v vf1 = *(const short8v*)&Vlds[jh][cur][r1 * 64 + (((c * 2 + hq) ^ (r1 & 7)) << 3)];
            accO[0][0] = MFMA32(pa0.s, vf0, accO[0][0]);
            accO[0][1] = MFMA32(pa0.s, vf1, accO[0][1]);
            accO[1][0] = MFMA32(pa1.s, vf0, accO[1][0]);
            accO[1][1] = MFMA32(pa1.s, vf1, accO[1][1]);
        }
        __builtin_amdgcn_s_setprio(0);
        SBAR();
        if (ltj + 2 < 16) AO_STAGE(cur, jh * 16 + ltj + 2);
        cur ^= 1;
    }

    // ---- combine j-halves via LDS (stride-67 pad: conflict-free) ----
    if (jh == 1) {
        float* cb = &comb[iwv][lane * 67];
        #pragma unroll
        for (int g = 0; g < 2; ++g)
            #pragma unroll
            for (int h = 0; h < 2; ++h)
                #pragma unroll
                for (int r = 0; r < 16; ++r)
                    cb[(g * 2 + h) * 16 + r] = accO[g][h][r];
    }
    __syncthreads();
    if (jh == 0) {
        const float* cb = &comb[iwv][lane * 67];
        #pragma unroll
        for (int g = 0; g < 2; ++g)
            #pragma unroll
            for (int h = 0; h < 2; ++h)
                #pragma unroll
                for (int r = 0; r < 16; ++r)
                    accO[g][h][r] += cb[(g * 2 + h) * 16 + r];

        #pragma unroll
        for (int ig = 0; ig < 2; ++ig) {
            #pragma unroll
            for (int q = 0; q < 4; ++q) {
                float4 xq = *(const float4*)&x[(size_t)b * L_ + iw + ig * 32 + 4 * hq + 8 * q];
                const float xs[4] = { xq.x, xq.y, xq.z, xq.w };
                #pragma unroll
                for (int k = 0; k < 4; ++k) {
                    int r    = q * 4 + k;
                    int irow = iw + ig * 32 + 4 * hq + 8 * q + k;
                    size_t base = ((size_t)b * L_ + irow) * E_ + hh * DH_;
                    Of[base + l31]      = (_Float16)(accO[ig][0][r] * xs[k]);
                    Of[base + 32 + l31] = (_Float16)(accO[ig][1][r] * xs[k]);
                }
            }
        }
    }
#undef AO_STAGE
}

// ---------------------------------------------------------------------------
// Kernel 5: fused MLP, fp16 MFMA, 128x128, BK=64, counted-vmcnt pipeline.
// y is pre-zeroed (memset); b2 folded into the blockIdx.y==0 contribution.
// ---------------------------------------------------------------------------
__global__ __launch_bounds__(256) void mlp_mfma(
    const _Float16* __restrict__ Of, const _Float16* __restrict__ W1t,
    const float* __restrict__ b1, const float* __restrict__ W2,
    const float* __restrict__ b2, float* __restrict__ y)
{
    __shared__ _Float16 Oh[2][128 * 64];
    __shared__ _Float16 Wh[2][128 * 64];

    const int t    = threadIdx.x;
    const int lane = t & 63;
    const int w    = t >> 6;
    const int l31  = lane & 31;
    const int hq   = lane >> 5;
    const int wm   = w >> 1, wn = w & 1;
    const int m0   = blockIdx.x * 128;
    const int n0   = blockIdx.y * 128;

    const int srow0 = (lane >> 3);
    const int ssl   = lane & 7;

    f32x16 acc[2][2] = {};

#define MLP_STAGE(bb, kc)                                                          \
    {                                                                              \
        _Pragma("unroll")                                                          \
        for (int u = 0; u < 4; ++u) {                                              \
            int ch  = w * 4 + u;                                                   \
            int row = ch * 8 + srow0;                                              \
            gl_lds16(&Of[(size_t)(m0 + row) * E_ + (kc) * 64 + ((ssl ^ (row & 7)) << 3)], \
                     &Oh[bb][ch * 512]);                                           \
            gl_lds16(&W1t[(size_t)(n0 + row) * E_ + (kc) * 64 + ((ssl ^ (row & 7)) << 3)], \
                     &Wh[bb][ch * 512]);                                           \
        }                                                                          \
    }

    MLP_STAGE(0, 0);
    MLP_STAGE(1, 1);
    __syncthreads();
    int cur = 0;

    for (int kc = 0; kc < 16; ++kc) {
        if (kc < 15) WAITV(8); else WAITV(0);
        SBAR();
        __builtin_amdgcn_s_setprio(1);
        #pragma unroll
        for (int ks = 0; ks < 4; ++ks) {
            half8v fb[2];
            #pragma unroll
            for (int nb = 0; nb < 2; ++nb) {
                int br = wn * 64 + nb * 32 + l31;
                fb[nb] = *(const half8v*)&Wh[cur][br * 64 + (((ks * 2 + hq) ^ (br & 7)) << 3)];
            }
            #pragma unroll
            for (int mb = 0; mb < 2; ++mb) {
                int ar = wm * 64 + mb * 32 + l31;
                half8v fa = *(const half8v*)&Oh[cur][ar * 64 + (((ks * 2 + hq) ^ (ar & 7)) << 3)];
                acc[mb][0] = MFMAH(fa, fb[0], acc[mb][0]);
                acc[mb][1] = MFMAH(fa, fb[1], acc[mb][1]);
            }
        }
        __builtin_amdgcn_s_setprio(0);
        SBAR();
        if (kc + 2 < 16) MLP_STAGE(cur, kc + 2);
        cur ^= 1;
    }

    // epilogue: gelu + W2 dot; reduce over 32 lanes; atomicAdd per row.
    const int hid0 = n0 + wn * 64 + l31;
    const float bb0 = b1[hid0],      w20 = W2[hid0];
    const float bb1 = b1[hid0 + 32], w21 = W2[hid0 + 32];
    const float b2v = (blockIdx.y == 0) ? b2[0] : 0.0f;
    #pragma unroll
    for (int mb = 0; mb < 2; ++mb) {
        #pragma unroll
        for (int r = 0; r < 16; ++r) {
            float h0 = acc[mb][0][r] + bb0;
            float h1 = acc[mb][1][r] + bb1;
            float s  = 0.5f * h0 * (1.0f + erf_fast(h0 * 0.70710678f)) * w20
                     + 0.5f * h1 * (1.0f + erf_fast(h1 * 0.70710678f)) * w21;
            #pragma unroll
            for (int off = 16; off > 0; off >>= 1) s += __shfl_xor(s, off);
            if (l31 == 0) {
                int m = m0 + wm * 64 + mb * 32 + (r & 3) + 8 * (r >> 2) + 4 * hq;
                atomicAdd(&y[m], s + b2v);
            }
        }
    }
#undef MLP_STAGE
}

// ---------------------------------------------------------------------------
extern "C" void kernel_launch(void* const* d_in, const int* in_sizes, int n_in,
                              void* d_out, int out_size, void* d_ws, size_t ws_size,
                              hipStream_t stream)
{
    const float* x  = (const float*)d_in[0];
    const float* z  = (const float*)d_in[1];
    const float* Wq = (const float*)d_in[2];
    const float* bq = (const float*)d_in[3];
    const float* Wk = (const float*)d_in[4];
    const float* bk = (const float*)d_in[5];
    const float* Wv = (const float*)d_in[6];
    const float* bv = (const float*)d_in[7];
    const float* W1 = (const float*)d_in[8];
    const float* b1 = (const float*)d_in[9];
    const float* W2 = (const float*)d_in[10];
    const float* b2 = (const float*)d_in[11];
    float* y = (float*)d_out;

    const size_t NQ = (size_t)BH_ * L_ * DH_;        // 4.19M elems
    unsigned short* p = (unsigned short*)d_ws;
    unsigned short* Qb  = p;  p += NQ;               // Qb|Kb|Vb contiguous
    unsigned short* Kb  = p;  p += NQ;
    unsigned short* Vb  = p;  p += NQ;
    unsigned short* Vt  = p;  p += NQ;
    _Float16* zh  = (_Float16*)p;  p += (size_t)NROW_ * E_;
    _Float16* Tq  = (_Float16*)p;  p += (size_t)E_ * E_;   // Tq|Tk|Tv contiguous
    _Float16* Tk  = (_Float16*)p;  p += (size_t)E_ * E_;
    _Float16* Tv  = (_Float16*)p;  p += (size_t)E_ * E_;
    _Float16* W1t = (_Float16*)p;  p += (size_t)HID_ * E_;
    _Float16* Ofp = (_Float16*)p;  p += (size_t)NROW_ * E_;
    float* Dw = (float*)p;

    hipMemsetAsync(y, 0, (size_t)out_size * sizeof(float), stream);

    zh_prep<<<dim3((NROW_ * E_) / (256 * 8)), 256, 0, stream>>>(z, zh);
    wprep3 <<<dim3(E_ / 64, E_ / 64, 3), 256, 0, stream>>>(Wq, Wk, Wv, Tq, Tk, Tv);
    w1prep <<<dim3(HID_ / 64, E_ / 64), 256, 0, stream>>>(W1, W1t);

    qkv_mfma<<<dim3(NROW_ / 128, 3 * E_ / 128), 256, 0, stream>>>(
        zh, Tq, bq, bk, bv, Qb);

    col_stats_mfma<<<dim3(L_ / 256, BH_), 512, 0, stream>>>(Qb, Kb, x, Dw);

    vt_prep<<<dim3(L_ / 64, BH_), 256, 0, stream>>>(Vb, x, Dw, Vt);

    attn_out_mfma<<<dim3(L_ / 256, BH_), 512, 0, stream>>>(Qb, Kb, Vt, x, Ofp);

    mlp_mfma<<<dim3(NROW_ / 128, HID_ / 128), 256, 0, stream>>>(
        Ofp, W1t, b1, W2, b2, y);
}